// Round 14
// baseline (1922.961 us; speedup 1.0000x reference)
//
#include <hip/hip_runtime.h>
#include <math.h>

#define H 128
#define H2 256
#define LDK 72   // LDS row stride (bf16) for 64-wide k rows
#define LDH 264  // LDS row stride (bf16) for the fused hidden (256 k)
#define LDC 136  // LDS row stride (bf16) for conv weight rows (128 k)
#define FFN_SMEM (64 * LDH + H * LDK)  // 26112 shorts = 52224 B

typedef __attribute__((ext_vector_type(8))) short short8;
typedef __attribute__((ext_vector_type(4))) float floatx4;

// fast GELU: x * sigmoid(1.5957691*x*(1+0.044715*x^2)); max |dev| from exact erf-GELU ~1e-3,
// negligible vs the bf16-rounding error budget (absmax 16 vs threshold 34.7)
__device__ __forceinline__ float gelu_f(float x) {
  float t = 1.59576912161f * x * fmaf(0.044715f, x * x, 1.0f);
  return x / (1.0f + __expf(-t));
}

__device__ __forceinline__ unsigned short f2b(float f) {
  union { float f; unsigned u; } c; c.f = f;
  unsigned r = c.u + 0x7fffu + ((c.u >> 16) & 1u);
  return (unsigned short)(r >> 16);
}

__device__ __forceinline__ float b2f(unsigned short u) {
  union { unsigned u; float f; } c; c.u = ((unsigned)u) << 16; return c.f;
}

__device__ __forceinline__ short8 pack8(floatx4 a, floatx4 b) {
  union { short8 v; unsigned short s[8]; } u;
  u.s[0] = f2b(a.x); u.s[1] = f2b(a.y); u.s[2] = f2b(a.z); u.s[3] = f2b(a.w);
  u.s[4] = f2b(b.x); u.s[5] = f2b(b.y); u.s[6] = f2b(b.z); u.s[7] = f2b(b.w);
  return u.v;
}

// ---------------- weight transpose+convert: W[b][K][N] fp32 -> WT[b][N][K] bf16 ----------------
__global__ __launch_bounds__(256) void transpose_w(const float* __restrict__ W, unsigned short* __restrict__ WT,
                                                   int K, int Ncol, int total) {
  int i = blockIdx.x * 256 + threadIdx.x;
  if (i >= total) return;
  int kn = K * Ncol;
  int b = i / kn, r = i - b * kn;
  int k = r / Ncol, n = r - k * Ncol;
  WT[b * kn + n * K + k] = f2b(W[i]);
}

// ---------------- CSR build ----------------

__global__ __launch_bounds__(256) void hist_kernel(int* __restrict__ cnt, const int* __restrict__ dst, int E) {
  int i = blockIdx.x * 256 + threadIdx.x;
  if (i < E) atomicAdd(&cnt[dst[i]], 1);
}

__global__ __launch_bounds__(256) void scan_a(const int* __restrict__ cnt, int* __restrict__ row_ptr,
                                              int* __restrict__ blockSum, float* __restrict__ dinv, int N) {
  __shared__ int ls[256];
  int t = threadIdx.x;
  int idx = blockIdx.x * 1024 + t * 4;
  int4 v = make_int4(0, 0, 0, 0);
  if (idx + 3 < N) v = *(const int4*)&cnt[idx];
  else {
    if (idx + 0 < N) v.x = cnt[idx + 0];
    if (idx + 1 < N) v.y = cnt[idx + 1];
    if (idx + 2 < N) v.z = cnt[idx + 2];
    if (idx + 3 < N) v.w = cnt[idx + 3];
  }
  if (idx + 0 < N) dinv[idx + 0] = rsqrtf((float)v.x + 1.0f);
  if (idx + 1 < N) dinv[idx + 1] = rsqrtf((float)v.y + 1.0f);
  if (idx + 2 < N) dinv[idx + 2] = rsqrtf((float)v.z + 1.0f);
  if (idx + 3 < N) dinv[idx + 3] = rsqrtf((float)v.w + 1.0f);
  int s = v.x + v.y + v.z + v.w;
  ls[t] = s;
  __syncthreads();
  for (int off = 1; off < 256; off <<= 1) {
    int a = (t >= off) ? ls[t - off] : 0;
    __syncthreads();
    ls[t] += a;
    __syncthreads();
  }
  int p = ls[t] - s;
  if (t == 255) blockSum[blockIdx.x] = ls[255];
  if (idx + 0 < N) row_ptr[idx + 0] = p;  p += v.x;
  if (idx + 1 < N) row_ptr[idx + 1] = p;  p += v.y;
  if (idx + 2 < N) row_ptr[idx + 2] = p;  p += v.z;
  if (idx + 3 < N) row_ptr[idx + 3] = p;
}

__global__ __launch_bounds__(1024) void scan_b(const int* __restrict__ blockSum, int* __restrict__ blockOff,
                                               int nb, int* __restrict__ row_ptr, int N, int E) {
  __shared__ int ls[1024];
  int t = threadIdx.x;
  int s = (t < nb) ? blockSum[t] : 0;
  ls[t] = s;
  __syncthreads();
  for (int off = 1; off < 1024; off <<= 1) {
    int a = (t >= off) ? ls[t - off] : 0;
    __syncthreads();
    ls[t] += a;
    __syncthreads();
  }
  if (t < nb) blockOff[t] = ls[t] - s;
  if (t == 0) row_ptr[N] = E;
}

__global__ __launch_bounds__(256) void scan_c(int* __restrict__ row_ptr, const int* __restrict__ blockOff, int N) {
  int t = threadIdx.x;
  int idx = blockIdx.x * 1024 + t * 4;
  int off = blockOff[blockIdx.x];
  if (off == 0) return;
  if (idx + 3 < N) {
    int4 v = *(const int4*)&row_ptr[idx];
    v.x += off; v.y += off; v.z += off; v.w += off;
    *(int4*)&row_ptr[idx] = v;
  } else {
    if (idx + 0 < N) row_ptr[idx + 0] += off;
    if (idx + 1 < N) row_ptr[idx + 1] += off;
    if (idx + 2 < N) row_ptr[idx + 2] += off;
    if (idx + 3 < N) row_ptr[idx + 3] += off;
  }
}

__global__ __launch_bounds__(256) void build_csr_kernel(const int* __restrict__ src, const int* __restrict__ dst,
                                                        const int* __restrict__ row_ptr, int* __restrict__ cursor,
                                                        const float* __restrict__ dinv,
                                                        int* __restrict__ csr_src, float* __restrict__ csr_norm,
                                                        int E) {
  int i = blockIdx.x * 256 + threadIdx.x;
  if (i < E) {
    int s = src[i], d = dst[i];
    int pos = row_ptr[d] + atomicAdd(&cursor[d], 1);
    csr_src[pos] = s;
    csr_norm[pos] = dinv[s] * dinv[d];
  }
}

// ---------------- small setup kernels ----------------

__global__ __launch_bounds__(256) void count_kernel(float* counts, const int* __restrict__ batch, int N, int G) {
  __shared__ float hist[256];
  int t = threadIdx.x;
  if (t < G) hist[t] = 0.f;
  __syncthreads();
  int i0 = (blockIdx.x * 256 + t) * 16;
  int cur = -1; float run = 0.f;
  for (int j = 0; j < 16; j++) {
    int i = i0 + j;
    if (i < N) {
      int b = batch[i];
      if (b == cur) run += 1.f;
      else { if (cur >= 0) atomicAdd(&hist[cur], run); cur = b; run = 1.f; }
    }
  }
  if (cur >= 0) atomicAdd(&hist[cur], run);
  __syncthreads();
  if (t < G && hist[t] != 0.f) atomicAdd(&counts[t], hist[t]);
}

__global__ __launch_bounds__(256) void vn_init_kernel(float* vn, const float* __restrict__ emb, int n) {
  int i = blockIdx.x * 256 + threadIdx.x;
  if (i < n) vn[i] = emb[i & (H - 1)];
}

// ---------------- fused gather aggregation (bf16 h) + BN stats ----------------
// 4-way edge unroll for memory-level parallelism (latency-bound kernel: the
// csr_src -> h-row dependent chain needs >=4 independent instances in flight).
__global__ __launch_bounds__(256) void gather_agg(const unsigned short* __restrict__ h, const int* __restrict__ csr_src,
                                                  const float* __restrict__ csr_norm, const int* __restrict__ row_ptr,
                                                  const float* __restrict__ dinv, const float* __restrict__ vn,
                                                  const int* __restrict__ batch, const float* __restrict__ bias,
                                                  float* __restrict__ x, float* __restrict__ stats, int N) {
  __shared__ float sred[4 * H];
  __shared__ float qred[4 * H];
  int w = threadIdx.x >> 6, lane = threadIdx.x & 63;
  int c = lane * 2;
  float2 bi = *(const float2*)&bias[c];
  float s0t = 0.f, s1t = 0.f, q0t = 0.f, q1t = 0.f;
  int base = blockIdx.x * 32 + w * 8;
  for (int j = 0; j < 8; j++) {
    int node = base + j;
    if (node >= N) break;
    // hoist epilogue operands: overlap their latency with the gather chain
    int b = batch[node];
    float di = dinv[node];
    float2 xo = *(const float2*)&x[(long)node * H + c];
    float2 vv = *(const float2*)&vn[b * H + c];
    unsigned hv = *(const unsigned*)&h[(long)node * H + c];
    int beg = row_ptr[node], end = row_ptr[node + 1];
    float ax = b2f((unsigned short)hv) * di * di;
    float ay = b2f((unsigned short)(hv >> 16)) * di * di;
    int e = beg;
    for (; e + 4 <= end; e += 4) {
      int sa = csr_src[e], sb = csr_src[e + 1], sc = csr_src[e + 2], sd = csr_src[e + 3];
      float w0 = csr_norm[e], w1 = csr_norm[e + 1], w2 = csr_norm[e + 2], w3 = csr_norm[e + 3];
      unsigned v0 = *(const unsigned*)&h[(long)sa * H + c];
      unsigned v1 = *(const unsigned*)&h[(long)sb * H + c];
      unsigned v2 = *(const unsigned*)&h[(long)sc * H + c];
      unsigned v3 = *(const unsigned*)&h[(long)sd * H + c];
      ax += b2f((unsigned short)v0) * w0 + b2f((unsigned short)v1) * w1
          + b2f((unsigned short)v2) * w2 + b2f((unsigned short)v3) * w3;
      ay += b2f((unsigned short)(v0 >> 16)) * w0 + b2f((unsigned short)(v1 >> 16)) * w1
          + b2f((unsigned short)(v2 >> 16)) * w2 + b2f((unsigned short)(v3 >> 16)) * w3;
    }
    for (; e + 2 <= end; e += 2) {
      int sa = csr_src[e], sb = csr_src[e + 1];
      float w0 = csr_norm[e], w1 = csr_norm[e + 1];
      unsigned v0 = *(const unsigned*)&h[(long)sa * H + c];
      unsigned v1 = *(const unsigned*)&h[(long)sb * H + c];
      ax += b2f((unsigned short)v0) * w0 + b2f((unsigned short)v1) * w1;
      ay += b2f((unsigned short)(v0 >> 16)) * w0 + b2f((unsigned short)(v1 >> 16)) * w1;
    }
    if (e < end) {
      int sa = csr_src[e];
      float w0 = csr_norm[e];
      unsigned v0 = *(const unsigned*)&h[(long)sa * H + c];
      ax += b2f((unsigned short)v0) * w0;
      ay += b2f((unsigned short)(v0 >> 16)) * w0;
    }
    float rx = ax + xo.x + vv.x + bi.x;
    float ry = ay + xo.y + vv.y + bi.y;
    *(float2*)&x[(long)node * H + c] = make_float2(rx, ry);
    s0t += rx; q0t += rx * rx;
    s1t += ry; q1t += ry * ry;
  }
  sred[w * H + c] = s0t; sred[w * H + c + 1] = s1t;
  qred[w * H + c] = q0t; qred[w * H + c + 1] = q1t;
  __syncthreads();
  int t = threadIdx.x;
  if (t < H) {
    float s = sred[t] + sred[H + t] + sred[2 * H + t] + sred[3 * H + t];
    if (s != 0.f) atomicAdd(&stats[t], s);
  } else {
    int cc = t - H;
    float q = qred[cc] + qred[H + cc] + qred[2 * H + cc] + qred[3 * H + cc];
    if (q != 0.f) atomicAdd(&stats[H + cc], q);
  }
}

// ---------------- BN finalize (stats -> scale/shift) ----------------
__global__ __launch_bounds__(128) void bn_finalize_kernel(const float* __restrict__ stats, const float* __restrict__ g,
                                                          const float* __restrict__ b, float* __restrict__ scsh,
                                                          float invN) {
  int c = threadIdx.x;
  float m = stats[c] * invN;
  float v = stats[H + c] * invN - m * m;
  float sc = rsqrtf(v + 1e-5f) * g[c];
  scsh[c] = sc;
  scsh[H + c] = b[c] - m * sc;
}

// ---------------- pooling (run-length over sorted batch) ----------------
__global__ __launch_bounds__(256) void pool_kernel(float* __restrict__ pooled, const float* __restrict__ x,
                                                   const int* __restrict__ batch, int N) {
  int c = threadIdx.x & 127;
  int slab = threadIdx.x >> 7;
  int r0 = blockIdx.x * 128 + slab;
  float acc = 0.f;
  int cur = -1;
  for (int k = 0; k < 64; k++) {
    int r = r0 + k * 2;
    if (r >= N) break;
    int b = batch[r];
    if (b != cur) {
      if (cur >= 0) atomicAdd(&pooled[cur * H + c], acc);
      cur = b; acc = 0.f;
    }
    acc += x[(long)r * H + c];
  }
  if (cur >= 0) atomicAdd(&pooled[cur * H + c], acc);
}

// ---------------- conv GEMM: B staged once in LDS, A direct->register, 1 barrier ----------------
__global__ __launch_bounds__(256) void conv_gemm(const float* __restrict__ x, const unsigned short* __restrict__ BT,
                                                 const float* __restrict__ vn, const int* __restrict__ batch,
                                                 unsigned short* __restrict__ h16, int M) {
  __shared__ unsigned short Bs[H * LDC];  // 34816 B
  int tid = threadIdx.x;
  int lane = tid & 63, w = tid >> 6;
  int row0 = blockIdx.x * 64;
  int mrow = lane & 15, quad = lane >> 4, cn = lane & 15;
  int arow = row0 + w * 16 + mrow;
  bool rin = arow < M;
  int b = rin ? batch[arow] : 0;

#pragma unroll
  for (int j = 0; j < 8; j++) {
    int chunk = j * 256 + tid;
    int n = chunk >> 4, k8 = (chunk & 15) * 8;
    *(short8*)&Bs[n * LDC + k8] = *(const short8*)&BT[(long)n * H + k8];
  }

  short8 af[4];
#pragma unroll
  for (int k0 = 0; k0 < 4; k0++) {
    int kb = k0 * 32 + quad * 8;
    floatx4 a0 = (floatx4)0.f, a1 = (floatx4)0.f;
    if (rin) {
      a0 = *(const floatx4*)&x[(long)arow * H + kb] + *(const floatx4*)&vn[b * H + kb];
      a1 = *(const floatx4*)&x[(long)arow * H + kb + 4] + *(const floatx4*)&vn[b * H + kb + 4];
    }
    af[k0] = pack8(a0, a1);
  }
  __syncthreads();

#pragma unroll
  for (int t = 0; t < 8; t++) {
    floatx4 a = (floatx4)0.f;
#pragma unroll
    for (int k0 = 0; k0 < 4; k0++) {
      int kb = k0 * 32 + quad * 8;
      short8 bf = *(const short8*)&Bs[(t * 16 + mrow) * LDC + kb];
      a = __builtin_amdgcn_mfma_f32_16x16x32_bf16(af[k0], bf, a, 0, 0, 0);
    }
    int c = t * 16 + cn;
#pragma unroll
    for (int i = 0; i < 4; i++) {
      int r = row0 + w * 16 + quad * 4 + i;
      if (r < M) h16[(long)r * H + c] = f2b(a[i]);
    }
  }
}

// ---------------- fused 2-layer FFN: B staged in 64-k slices, A direct ----------------
template <int BNRES>
__global__ __launch_bounds__(256) void ffn_fused(const float* __restrict__ A,
                                                 const unsigned short* __restrict__ W1T, const float* __restrict__ b1,
                                                 const unsigned short* __restrict__ W2T, const float* __restrict__ b2,
                                                 const float* __restrict__ scsh,
                                                 float* __restrict__ C, int M) {
  __shared__ unsigned short smem[FFN_SMEM];  // 26112 shorts = 52224 B
  unsigned short* Bs1 = smem;                // phase 1: 256 rows x 64-k slice (LDK)
  unsigned short* Hs  = smem;                // phase 2: 64 x LDH (0..16896)
  unsigned short* Bs2 = smem + 64 * LDH;     // phase 2: 128 rows x 64-k slice (16896..26112)

  int tid = threadIdx.x;
  int lane = tid & 63, w = tid >> 6;
  int row0 = blockIdx.x * 64;
  int mrow = lane & 15, quad = lane >> 4, cn = lane & 15;
  int arow = row0 + w * 16 + mrow;
  bool rin = arow < M;

  short8 af[4];
#pragma unroll
  for (int k0 = 0; k0 < 4; k0++) {
    int kb = k0 * 32 + quad * 8;
    floatx4 a0 = (floatx4)0.f, a1 = (floatx4)0.f;
    if (rin) {
      a0 = *(const floatx4*)&A[(long)arow * H + kb];
      a1 = *(const floatx4*)&A[(long)arow * H + kb + 4];
      if (BNRES) {
        a0 = a0 * *(const floatx4*)&scsh[kb] + *(const floatx4*)&scsh[H + kb];
        a1 = a1 * *(const floatx4*)&scsh[kb + 4] + *(const floatx4*)&scsh[H + kb + 4];
      }
    }
    af[k0] = pack8(a0, a1);
  }

  floatx4 acc1[16];
#pragma unroll
  for (int t = 0; t < 16; t++) acc1[t] = (floatx4)0.f;

  for (int ks = 0; ks < 2; ks++) {
    if (ks > 0) __syncthreads();
#pragma unroll
    for (int j = 0; j < 8; j++) {
      int chunk = j * 256 + tid;
      int n = chunk >> 3, k8 = (chunk & 7) * 8;
      *(short8*)&Bs1[n * LDK + k8] = *(const short8*)&W1T[(long)n * H + ks * 64 + k8];
    }
    __syncthreads();
#pragma unroll
    for (int t = 0; t < 16; t++) {
      int kb = quad * 8;
      short8 bf0 = *(const short8*)&Bs1[(t * 16 + mrow) * LDK + kb];
      acc1[t] = __builtin_amdgcn_mfma_f32_16x16x32_bf16(af[ks * 2], bf0, acc1[t], 0, 0, 0);
      short8 bf1 = *(const short8*)&Bs1[(t * 16 + mrow) * LDK + 32 + kb];
      acc1[t] = __builtin_amdgcn_mfma_f32_16x16x32_bf16(af[ks * 2 + 1], bf1, acc1[t], 0, 0, 0);
    }
  }
  __syncthreads();

#pragma unroll
  for (int t = 0; t < 16; t++) {
    int c = t * 16 + cn;
    float bb = b1[c];
#pragma unroll
    for (int i = 0; i < 4; i++) {
      int r = w * 16 + quad * 4 + i;
      Hs[r * LDH + c] = f2b(gelu_f(acc1[t][i] + bb));
    }
  }
#pragma unroll
  for (int j = 0; j < 4; j++) {
    int chunk = j * 256 + tid;
    int n = chunk >> 3, k8 = (chunk & 7) * 8;
    *(short8*)&Bs2[n * LDK + k8] = *(const short8*)&W2T[(long)n * H2 + k8];
  }
  __syncthreads();

  short8 hf[8];
#pragma unroll
  for (int k0 = 0; k0 < 8; k0++)
    hf[k0] = *(const short8*)&Hs[(w * 16 + mrow) * LDH + k0 * 32 + quad * 8];

  floatx4 acc2[8];
#pragma unroll
  for (int t = 0; t < 8; t++) acc2[t] = (floatx4)0.f;

  for (int ks = 0; ks < 4; ks++) {
    if (ks > 0) {
      __syncthreads();
#pragma unroll
      for (int j = 0; j < 4; j++) {
        int chunk = j * 256 + tid;
        int n = chunk >> 3, k8 = (chunk & 7) * 8;
        *(short8*)&Bs2[n * LDK + k8] = *(const short8*)&W2T[(long)n * H2 + ks * 64 + k8];
      }
      __syncthreads();
    }
    int kk = ks * 2;
#pragma unroll
    for (int t = 0; t < 8; t++) {
      int kb0 = quad * 8;
      short8 bf0 = *(const short8*)&Bs2[(t * 16 + mrow) * LDK + kb0];
      acc2[t] = __builtin_amdgcn_mfma_f32_16x16x32_bf16(hf[kk], bf0, acc2[t], 0, 0, 0);
      short8 bf1 = *(const short8*)&Bs2[(t * 16 + mrow) * LDK + 32 + kb0];
      acc2[t] = __builtin_amdgcn_mfma_f32_16x16x32_bf16(hf[kk + 1], bf1, acc2[t], 0, 0, 0);
    }
  }

#pragma unroll
  for (int t = 0; t < 8; t++) {
    int c = t * 16 + cn;
    float bb = b2[c];
    float rsc = 0.f, rsh = 0.f;
    if (BNRES) { rsc = scsh[c]; rsh = scsh[H + c]; }
#pragma unroll
    for (int i = 0; i < 4; i++) {
      int r = row0 + w * 16 + quad * 4 + i;
      if (r < M) {
        long off = (long)r * H + c;
        float v = gelu_f(acc2[t][i] + bb);
        if (BNRES) v += C[off] * rsc + rsh;
        C[off] = v;
      }
    }
  }
}

// ---------------- parallel 64-row MLP stages (vn / post) ----------------
template <int BN, int UVN>
__global__ __launch_bounds__(256) void mlp64_l1(const float* __restrict__ vn, const float* __restrict__ pooled,
                                                const float* __restrict__ counts,
                                                const float* __restrict__ W1, const float* __restrict__ b1,
                                                const float* __restrict__ g1, const float* __restrict__ be1,
                                                float* __restrict__ h1) {
  __shared__ float u[64 * H];
  __shared__ float red[8 * 64];
  int t = threadIdx.x;
  for (int idx = t; idx < 64 * H; idx += 256) {
    float v = pooled[idx];
    if (UVN) v = vn[idx] + v / fmaxf(counts[idx >> 7], 1.0f);
    u[idx] = v;
  }
  __syncthreads();
  int tc = t & 63, tg = t >> 6;
  int c = blockIdx.x * 64 + tc;
  float acc[16];
  float bj = b1[c];
#pragma unroll
  for (int g = 0; g < 16; g++) acc[g] = bj;
  for (int k0 = 0; k0 < H; k0 += 4) {
    float w0 = W1[(k0 + 0) * H2 + c];
    float w1 = W1[(k0 + 1) * H2 + c];
    float w2 = W1[(k0 + 2) * H2 + c];
    float w3 = W1[(k0 + 3) * H2 + c];
#pragma unroll
    for (int g = 0; g < 16; g++) {
      float4 v = *(const float4*)&u[(tg * 16 + g) * H + k0];
      acc[g] += v.x * w0 + v.y * w1 + v.z * w2 + v.w * w3;
    }
  }
  float sc = 1.f, sh = 0.f;
  if (BN) {
    float s = 0.f, s2 = 0.f;
#pragma unroll
    for (int g = 0; g < 16; g++) { s += acc[g]; s2 += acc[g] * acc[g]; }
    red[tg * 64 + tc] = s;
    red[256 + tg * 64 + tc] = s2;
    __syncthreads();
    float st = red[tc] + red[64 + tc] + red[128 + tc] + red[192 + tc];
    float st2 = red[256 + tc] + red[320 + tc] + red[384 + tc] + red[448 + tc];
    float m = st * (1.f / 64.f);
    float var = st2 * (1.f / 64.f) - m * m;
    sc = rsqrtf(var + 1e-5f) * g1[c];
    sh = be1[c] - m * sc;
  }
#pragma unroll
  for (int g = 0; g < 16; g++) h1[(tg * 16 + g) * H2 + c] = gelu_f(acc[g] * sc + sh);
}

template <int BN>
__global__ __launch_bounds__(256) void mlp64_l2(const float* __restrict__ h1,
                                                const float* __restrict__ W2, const float* __restrict__ b2,
                                                const float* __restrict__ g2, const float* __restrict__ be2,
                                                float* __restrict__ outp) {
  __shared__ float red[8 * 64];
  int t = threadIdx.x;
  int tc = t & 63, tg = t >> 6;
  int c = blockIdx.x * 64 + tc;
  float acc[16];
  float bj = b2[c];
#pragma unroll
  for (int g = 0; g < 16; g++) acc[g] = bj;
  for (int k0 = 0; k0 < H2; k0 += 4) {
    float w0 = W2[(k0 + 0) * H + c];
    float w1 = W2[(k0 + 1) * H + c];
    float w2 = W2[(k0 + 2) * H + c];
    float w3 = W2[(k0 + 3) * H + c];
#pragma unroll
    for (int g = 0; g < 16; g++) {
      float4 v = *(const float4*)&h1[(tg * 16 + g) * H2 + k0];
      acc[g] += v.x * w0 + v.y * w1 + v.z * w2 + v.w * w3;
    }
  }
  float sc = 1.f, sh = 0.f;
  if (BN) {
    float s = 0.f, s2 = 0.f;
#pragma unroll
    for (int g = 0; g < 16; g++) { s += acc[g]; s2 += acc[g] * acc[g]; }
    red[tg * 64 + tc] = s;
    red[256 + tg * 64 + tc] = s2;
    __syncthreads();
    float st = red[tc] + red[64 + tc] + red[128 + tc] + red[192 + tc];
    float st2 = red[256 + tc] + red[320 + tc] + red[384 + tc] + red[448 + tc];
    float m = st * (1.f / 64.f);
    float var = st2 * (1.f / 64.f) - m * m;
    sc = rsqrtf(var + 1e-5f) * g2[c];
    sh = be2[c] - m * sc;
  }
#pragma unroll
  for (int g = 0; g < 16; g++) outp[(tg * 16 + g) * H + c] = gelu_f(acc[g] * sc + sh);
}

// ---------------- host launch ----------------

extern "C" void kernel_launch(void* const* d_in, const int* in_sizes, int n_in,
                              void* d_out, int out_size, void* d_ws, size_t ws_size,
                              hipStream_t stream) {
  const float* x_in   = (const float*)d_in[0];
  const int*   edge   = (const int*)d_in[1];
  const int*   batch  = (const int*)d_in[2];
  const float* pre_W1 = (const float*)d_in[3];
  const float* pre_b1 = (const float*)d_in[4];
  const float* pre_W2 = (const float*)d_in[5];
  const float* pre_b2 = (const float*)d_in[6];
  const float* conv_W = (const float*)d_in[7];
  const float* conv_b = (const float*)d_in[8];
  const float* bn_g   = (const float*)d_in[9];
  const float* bn_b   = (const float*)d_in[10];
  const float* ffn_W1 = (const float*)d_in[11];
  const float* ffn_b1 = (const float*)d_in[12];
  const float* ffn_W2 = (const float*)d_in[13];
  const float* ffn_b2 = (const float*)d_in[14];
  const float* vn_W1  = (const float*)d_in[15];
  const float* vn_b1  = (const float*)d_in[16];
  const float* vn_g1  = (const float*)d_in[17];
  const float* vn_be1 = (const float*)d_in[18];
  const float* vn_W2  = (const float*)d_in[19];
  const float* vn_b2  = (const float*)d_in[20];
  const float* vn_g2  = (const float*)d_in[21];
  const float* vn_be2 = (const float*)d_in[22];
  const float* vn_emb = (const float*)d_in[23];
  const float* post_W1= (const float*)d_in[24];
  const float* post_b1= (const float*)d_in[25];
  const float* post_W2= (const float*)d_in[26];
  const float* post_b2= (const float*)d_in[27];
  float* out = (float*)d_out;

  const int N    = in_sizes[2];
  const int E    = in_sizes[1] / 2;
  const int G    = out_size / H;
  const int HOPS = in_sizes[7] / (H * H);
  const int NH   = N * H;

  // workspace layout
  float* w = (float*)d_ws;
  float* buf_x  = w;  w += NH;
  float* buf_t  = w;  w += N * H2;
  unsigned short* buf_h16 = (unsigned short*)buf_t;
  float* dinv   = w;  w += N;
  float* counts = w;  w += G;
  float* stats  = w;  w += 2 * H;
  float* scsh   = w;  w += 2 * H;
  float* pooled = w;  w += G * H;
  float* vn     = w;  w += G * H;
  float* mlp_h1 = w;  w += G * H2;
  float* csr_norm = w; w += E;
  int* iw = (int*)w;
  int* cnt      = iw;  iw += N;
  int* row_ptr  = iw;  iw += N + 1;
  int* cursor   = iw;  iw += N;
  int* csr_src  = iw;  iw += E;
  int* blockSum = iw;  iw += 1024;
  int* blockOff = iw;  iw += 1024;
  unsigned short* wt = (unsigned short*)iw;
  unsigned short* preW1T = wt;  wt += H * H2;
  unsigned short* preW2T = wt;  wt += H2 * H;
  unsigned short* convT  = wt;  wt += HOPS * H * H;
  unsigned short* ffn1T  = wt;  wt += HOPS * H * H2;
  unsigned short* ffn2T  = wt;  wt += HOPS * H2 * H;

  const int* src = edge;
  const int* dst = edge + E;

  int gE  = (E + 255) / 256;
  int gM  = (N + 63) / 64;
  int nb  = (N + 1023) / 1024;
  float invN = 1.0f / (float)N;

  // weight transposes
  transpose_w<<<(H * H2 + 255) / 256, 256, 0, stream>>>(pre_W1, preW1T, H, H2, H * H2);
  transpose_w<<<(H2 * H + 255) / 256, 256, 0, stream>>>(pre_W2, preW2T, H2, H, H2 * H);
  transpose_w<<<(HOPS * H * H + 255) / 256, 256, 0, stream>>>(conv_W, convT, H, H, HOPS * H * H);
  transpose_w<<<(HOPS * H * H2 + 255) / 256, 256, 0, stream>>>(ffn_W1, ffn1T, H, H2, HOPS * H * H2);
  transpose_w<<<(HOPS * H2 * H + 255) / 256, 256, 0, stream>>>(ffn_W2, ffn2T, H2, H, HOPS * H2 * H);

  // CSR build + dinv
  hipMemsetAsync(cnt, 0, N * sizeof(int), stream);
  hist_kernel<<<gE, 256, 0, stream>>>(cnt, dst, E);
  scan_a<<<nb, 256, 0, stream>>>(cnt, row_ptr, blockSum, dinv, N);
  scan_b<<<1, 1024, 0, stream>>>(blockSum, blockOff, nb, row_ptr, N, E);
  scan_c<<<nb, 256, 0, stream>>>(row_ptr, blockOff, N);
  hipMemsetAsync(cursor, 0, N * sizeof(int), stream);
  build_csr_kernel<<<gE, 256, 0, stream>>>(src, dst, row_ptr, cursor, dinv, csr_src, csr_norm, E);

  // graph counts, vn init
  hipMemsetAsync(counts, 0, G * sizeof(float), stream);
  count_kernel<<<(N + 256 * 16 - 1) / (256 * 16), 256, 0, stream>>>(counts, batch, N, G);
  vn_init_kernel<<<(G * H + 255) / 256, 256, 0, stream>>>(vn, vn_emb, G * H);

  // pre-FFNN (fused pair)
  ffn_fused<0><<<gM, 256, 0, stream>>>(x_in, preW1T, pre_b1, preW2T, pre_b2, nullptr, buf_x, N);

  for (int i = 0; i < HOPS; i++) {
    // GCN: h16 = bf16( (x + vn[batch]) @ W )
    conv_gemm<<<gM, 256, 0, stream>>>(buf_x, convT + i * H * H, vn, batch, buf_h16, N);
    // x = x + vn[batch] + bias + selfloop + gathered edges; BN stats fused
    hipMemsetAsync(stats, 0, 2 * H * sizeof(float), stream);
    gather_agg<<<(N + 31) / 32, 256, 0, stream>>>(buf_h16, csr_src, csr_norm, row_ptr, dinv, vn, batch,
                                                  conv_b + i * H, buf_x, stats, N);
    bn_finalize_kernel<<<1, 128, 0, stream>>>(stats, bn_g + i * H, bn_b + i * H, scsh, invN);
    // fused FFN: x = gelu(gelu(bn(x)@W1+b1)@W2+b2) + bn(x)
    ffn_fused<1><<<gM, 256, 0, stream>>>(buf_x, ffn1T + i * H * H2, ffn_b1 + i * H2,
                                         ffn2T + i * H2 * H, ffn_b2 + i * H, scsh, buf_x, N);
    // virtual node update
    if (i < HOPS - 1) {
      hipMemsetAsync(pooled, 0, G * H * sizeof(float), stream);
      pool_kernel<<<(N + 127) / 128, 256, 0, stream>>>(pooled, buf_x, batch, N);
      mlp64_l1<1, 1><<<H2 / 64, 256, 0, stream>>>(vn, pooled, counts,
                                                  vn_W1 + i * H * H2, vn_b1 + i * H2, vn_g1 + i * H2, vn_be1 + i * H2,
                                                  mlp_h1);
      mlp64_l2<1><<<H / 64, 256, 0, stream>>>(mlp_h1, vn_W2 + i * H2 * H, vn_b2 + i * H, vn_g2 + i * H, vn_be2 + i * H, vn);
    }
  }

  // final global_add_pool + post-FFNN
  hipMemsetAsync(pooled, 0, G * H * sizeof(float), stream);
  pool_kernel<<<(N + 127) / 128, 256, 0, stream>>>(pooled, buf_x, batch, N);
  mlp64_l1<0, 0><<<H2 / 64, 256, 0, stream>>>(nullptr, pooled, nullptr, post_W1, post_b1, nullptr, nullptr, mlp_h1);
  mlp64_l2<0><<<H / 64, 256, 0, stream>>>(mlp_h1, post_W2, post_b2, nullptr, nullptr, out);
}

// Round 15
// 1896.216 us; speedup vs baseline: 1.0141x; 1.0141x over previous
//
#include <hip/hip_runtime.h>
#include <math.h>

#define H 128
#define H2 256
#define LDK 72    // LDS row stride (bf16) for 64-wide k rows
#define LDC 136   // LDS row stride (bf16) for conv weight rows (128 k)
#define LDHW 136  // LDS row stride (bf16) for per-wave hidden half (128 cols)
// ffn_fused LDS: Bs1 = 256*LDK = 18432 sh; overlay { per-wave Hs 4*16*LDHW = 8704 sh | Bs2 128*LDK = 9216 sh }
#define FFN_SMEM (H2 * LDK)  // 18432 shorts = 36864 B -> 4 blocks/CU

typedef __attribute__((ext_vector_type(8))) short short8;
typedef __attribute__((ext_vector_type(4))) float floatx4;

// fast GELU: x * sigmoid(1.5957691*x*(1+0.044715*x^2)); max |dev| from exact erf-GELU ~1e-3,
// negligible vs the bf16-rounding error budget (absmax 16 vs threshold 34.7)
__device__ __forceinline__ float gelu_f(float x) {
  float t = 1.59576912161f * x * fmaf(0.044715f, x * x, 1.0f);
  return x / (1.0f + __expf(-t));
}

__device__ __forceinline__ unsigned short f2b(float f) {
  union { float f; unsigned u; } c; c.f = f;
  unsigned r = c.u + 0x7fffu + ((c.u >> 16) & 1u);
  return (unsigned short)(r >> 16);
}

__device__ __forceinline__ float b2f(unsigned short u) {
  union { unsigned u; float f; } c; c.u = ((unsigned)u) << 16; return c.f;
}

__device__ __forceinline__ short8 pack8(floatx4 a, floatx4 b) {
  union { short8 v; unsigned short s[8]; } u;
  u.s[0] = f2b(a.x); u.s[1] = f2b(a.y); u.s[2] = f2b(a.z); u.s[3] = f2b(a.w);
  u.s[4] = f2b(b.x); u.s[5] = f2b(b.y); u.s[6] = f2b(b.z); u.s[7] = f2b(b.w);
  return u.v;
}

// ---------------- weight transpose+convert: W[b][K][N] fp32 -> WT[b][N][K] bf16 ----------------
__global__ __launch_bounds__(256) void transpose_w(const float* __restrict__ W, unsigned short* __restrict__ WT,
                                                   int K, int Ncol, int total) {
  int i = blockIdx.x * 256 + threadIdx.x;
  if (i >= total) return;
  int kn = K * Ncol;
  int b = i / kn, r = i - b * kn;
  int k = r / Ncol, n = r - k * Ncol;
  WT[b * kn + n * K + k] = f2b(W[i]);
}

// ---------------- CSR build ----------------

__global__ __launch_bounds__(256) void hist_kernel(int* __restrict__ cnt, const int* __restrict__ dst, int E) {
  int i = blockIdx.x * 256 + threadIdx.x;
  if (i < E) atomicAdd(&cnt[dst[i]], 1);
}

__global__ __launch_bounds__(256) void scan_a(const int* __restrict__ cnt, int* __restrict__ row_ptr,
                                              int* __restrict__ blockSum, float* __restrict__ dinv, int N) {
  __shared__ int ls[256];
  int t = threadIdx.x;
  int idx = blockIdx.x * 1024 + t * 4;
  int4 v = make_int4(0, 0, 0, 0);
  if (idx + 3 < N) v = *(const int4*)&cnt[idx];
  else {
    if (idx + 0 < N) v.x = cnt[idx + 0];
    if (idx + 1 < N) v.y = cnt[idx + 1];
    if (idx + 2 < N) v.z = cnt[idx + 2];
    if (idx + 3 < N) v.w = cnt[idx + 3];
  }
  if (idx + 0 < N) dinv[idx + 0] = rsqrtf((float)v.x + 1.0f);
  if (idx + 1 < N) dinv[idx + 1] = rsqrtf((float)v.y + 1.0f);
  if (idx + 2 < N) dinv[idx + 2] = rsqrtf((float)v.z + 1.0f);
  if (idx + 3 < N) dinv[idx + 3] = rsqrtf((float)v.w + 1.0f);
  int s = v.x + v.y + v.z + v.w;
  ls[t] = s;
  __syncthreads();
  for (int off = 1; off < 256; off <<= 1) {
    int a = (t >= off) ? ls[t - off] : 0;
    __syncthreads();
    ls[t] += a;
    __syncthreads();
  }
  int p = ls[t] - s;
  if (t == 255) blockSum[blockIdx.x] = ls[255];
  if (idx + 0 < N) row_ptr[idx + 0] = p;  p += v.x;
  if (idx + 1 < N) row_ptr[idx + 1] = p;  p += v.y;
  if (idx + 2 < N) row_ptr[idx + 2] = p;  p += v.z;
  if (idx + 3 < N) row_ptr[idx + 3] = p;
}

__global__ __launch_bounds__(1024) void scan_b(const int* __restrict__ blockSum, int* __restrict__ blockOff,
                                               int nb, int* __restrict__ row_ptr, int N, int E) {
  __shared__ int ls[1024];
  int t = threadIdx.x;
  int s = (t < nb) ? blockSum[t] : 0;
  ls[t] = s;
  __syncthreads();
  for (int off = 1; off < 1024; off <<= 1) {
    int a = (t >= off) ? ls[t - off] : 0;
    __syncthreads();
    ls[t] += a;
    __syncthreads();
  }
  if (t < nb) blockOff[t] = ls[t] - s;
  if (t == 0) row_ptr[N] = E;
}

__global__ __launch_bounds__(256) void scan_c(int* __restrict__ row_ptr, const int* __restrict__ blockOff, int N) {
  int t = threadIdx.x;
  int idx = blockIdx.x * 1024 + t * 4;
  int off = blockOff[blockIdx.x];
  if (off == 0) return;
  if (idx + 3 < N) {
    int4 v = *(const int4*)&row_ptr[idx];
    v.x += off; v.y += off; v.z += off; v.w += off;
    *(int4*)&row_ptr[idx] = v;
  } else {
    if (idx + 0 < N) row_ptr[idx + 0] += off;
    if (idx + 1 < N) row_ptr[idx + 1] += off;
    if (idx + 2 < N) row_ptr[idx + 2] += off;
    if (idx + 3 < N) row_ptr[idx + 3] += off;
  }
}

__global__ __launch_bounds__(256) void build_csr_kernel(const int* __restrict__ src, const int* __restrict__ dst,
                                                        const int* __restrict__ row_ptr, int* __restrict__ cursor,
                                                        const float* __restrict__ dinv,
                                                        int* __restrict__ csr_src, float* __restrict__ csr_norm,
                                                        int E) {
  int i = blockIdx.x * 256 + threadIdx.x;
  if (i < E) {
    int s = src[i], d = dst[i];
    int pos = row_ptr[d] + atomicAdd(&cursor[d], 1);
    csr_src[pos] = s;
    csr_norm[pos] = dinv[s] * dinv[d];
  }
}

// ---------------- small setup kernels ----------------

__global__ __launch_bounds__(256) void count_kernel(float* counts, const int* __restrict__ batch, int N, int G) {
  __shared__ float hist[256];
  int t = threadIdx.x;
  if (t < G) hist[t] = 0.f;
  __syncthreads();
  int i0 = (blockIdx.x * 256 + t) * 16;
  int cur = -1; float run = 0.f;
  for (int j = 0; j < 16; j++) {
    int i = i0 + j;
    if (i < N) {
      int b = batch[i];
      if (b == cur) run += 1.f;
      else { if (cur >= 0) atomicAdd(&hist[cur], run); cur = b; run = 1.f; }
    }
  }
  if (cur >= 0) atomicAdd(&hist[cur], run);
  __syncthreads();
  if (t < G && hist[t] != 0.f) atomicAdd(&counts[t], hist[t]);
}

__global__ __launch_bounds__(256) void vn_init_kernel(float* vn, const float* __restrict__ emb, int n) {
  int i = blockIdx.x * 256 + threadIdx.x;
  if (i < n) vn[i] = emb[i & (H - 1)];
}

// ---------------- fused gather aggregation (bf16 h) + BN stats ----------------
__global__ __launch_bounds__(256) void gather_agg(const unsigned short* __restrict__ h, const int* __restrict__ csr_src,
                                                  const float* __restrict__ csr_norm, const int* __restrict__ row_ptr,
                                                  const float* __restrict__ dinv, const float* __restrict__ vn,
                                                  const int* __restrict__ batch, const float* __restrict__ bias,
                                                  float* __restrict__ x, float* __restrict__ stats, int N) {
  __shared__ float sred[4 * H];
  __shared__ float qred[4 * H];
  int w = threadIdx.x >> 6, lane = threadIdx.x & 63;
  int c = lane * 2;
  float2 bi = *(const float2*)&bias[c];
  float s0t = 0.f, s1t = 0.f, q0t = 0.f, q1t = 0.f;
  int base = blockIdx.x * 32 + w * 8;
  for (int j = 0; j < 8; j++) {
    int node = base + j;
    if (node >= N) break;
    int b = batch[node];
    float di = dinv[node];
    float2 xo = *(const float2*)&x[(long)node * H + c];
    float2 vv = *(const float2*)&vn[b * H + c];
    unsigned hv = *(const unsigned*)&h[(long)node * H + c];
    int beg = row_ptr[node], end = row_ptr[node + 1];
    float ax = b2f((unsigned short)hv) * di * di;
    float ay = b2f((unsigned short)(hv >> 16)) * di * di;
    int e = beg;
    for (; e + 4 <= end; e += 4) {
      int sa = csr_src[e], sb = csr_src[e + 1], sc = csr_src[e + 2], sd = csr_src[e + 3];
      float w0 = csr_norm[e], w1 = csr_norm[e + 1], w2 = csr_norm[e + 2], w3 = csr_norm[e + 3];
      unsigned v0 = *(const unsigned*)&h[(long)sa * H + c];
      unsigned v1 = *(const unsigned*)&h[(long)sb * H + c];
      unsigned v2 = *(const unsigned*)&h[(long)sc * H + c];
      unsigned v3 = *(const unsigned*)&h[(long)sd * H + c];
      ax += b2f((unsigned short)v0) * w0 + b2f((unsigned short)v1) * w1
          + b2f((unsigned short)v2) * w2 + b2f((unsigned short)v3) * w3;
      ay += b2f((unsigned short)(v0 >> 16)) * w0 + b2f((unsigned short)(v1 >> 16)) * w1
          + b2f((unsigned short)(v2 >> 16)) * w2 + b2f((unsigned short)(v3 >> 16)) * w3;
    }
    for (; e + 2 <= end; e += 2) {
      int sa = csr_src[e], sb = csr_src[e + 1];
      float w0 = csr_norm[e], w1 = csr_norm[e + 1];
      unsigned v0 = *(const unsigned*)&h[(long)sa * H + c];
      unsigned v1 = *(const unsigned*)&h[(long)sb * H + c];
      ax += b2f((unsigned short)v0) * w0 + b2f((unsigned short)v1) * w1;
      ay += b2f((unsigned short)(v0 >> 16)) * w0 + b2f((unsigned short)(v1 >> 16)) * w1;
    }
    if (e < end) {
      int sa = csr_src[e];
      float w0 = csr_norm[e];
      unsigned v0 = *(const unsigned*)&h[(long)sa * H + c];
      ax += b2f((unsigned short)v0) * w0;
      ay += b2f((unsigned short)(v0 >> 16)) * w0;
    }
    float rx = ax + xo.x + vv.x + bi.x;
    float ry = ay + xo.y + vv.y + bi.y;
    *(float2*)&x[(long)node * H + c] = make_float2(rx, ry);
    s0t += rx; q0t += rx * rx;
    s1t += ry; q1t += ry * ry;
  }
  sred[w * H + c] = s0t; sred[w * H + c + 1] = s1t;
  qred[w * H + c] = q0t; qred[w * H + c + 1] = q1t;
  __syncthreads();
  int t = threadIdx.x;
  if (t < H) {
    float s = sred[t] + sred[H + t] + sred[2 * H + t] + sred[3 * H + t];
    if (s != 0.f) atomicAdd(&stats[t], s);
  } else {
    int cc = t - H;
    float q = qred[cc] + qred[H + cc] + qred[2 * H + cc] + qred[3 * H + cc];
    if (q != 0.f) atomicAdd(&stats[H + cc], q);
  }
}

// ---------------- BN finalize (stats -> scale/shift) ----------------
__global__ __launch_bounds__(128) void bn_finalize_kernel(const float* __restrict__ stats, const float* __restrict__ g,
                                                          const float* __restrict__ b, float* __restrict__ scsh,
                                                          float invN) {
  int c = threadIdx.x;
  float m = stats[c] * invN;
  float v = stats[H + c] * invN - m * m;
  float sc = rsqrtf(v + 1e-5f) * g[c];
  scsh[c] = sc;
  scsh[H + c] = b[c] - m * sc;
}

// ---------------- pooling (run-length over sorted batch) ----------------
__global__ __launch_bounds__(256) void pool_kernel(float* __restrict__ pooled, const float* __restrict__ x,
                                                   const int* __restrict__ batch, int N) {
  int c = threadIdx.x & 127;
  int slab = threadIdx.x >> 7;
  int r0 = blockIdx.x * 128 + slab;
  float acc = 0.f;
  int cur = -1;
  for (int k = 0; k < 64; k++) {
    int r = r0 + k * 2;
    if (r >= N) break;
    int b = batch[r];
    if (b != cur) {
      if (cur >= 0) atomicAdd(&pooled[cur * H + c], acc);
      cur = b; acc = 0.f;
    }
    acc += x[(long)r * H + c];
  }
  if (cur >= 0) atomicAdd(&pooled[cur * H + c], acc);
}

// ---------------- conv GEMM: B staged once in LDS, A direct->register, 1 barrier ----------------
__global__ __launch_bounds__(256) void conv_gemm(const float* __restrict__ x, const unsigned short* __restrict__ BT,
                                                 const float* __restrict__ vn, const int* __restrict__ batch,
                                                 unsigned short* __restrict__ h16, int M) {
  __shared__ unsigned short Bs[H * LDC];  // 34816 B
  int tid = threadIdx.x;
  int lane = tid & 63, w = tid >> 6;
  int row0 = blockIdx.x * 64;
  int mrow = lane & 15, quad = lane >> 4, cn = lane & 15;
  int arow = row0 + w * 16 + mrow;
  bool rin = arow < M;
  int b = rin ? batch[arow] : 0;

#pragma unroll
  for (int j = 0; j < 8; j++) {
    int chunk = j * 256 + tid;
    int n = chunk >> 4, k8 = (chunk & 15) * 8;
    *(short8*)&Bs[n * LDC + k8] = *(const short8*)&BT[(long)n * H + k8];
  }

  short8 af[4];
#pragma unroll
  for (int k0 = 0; k0 < 4; k0++) {
    int kb = k0 * 32 + quad * 8;
    floatx4 a0 = (floatx4)0.f, a1 = (floatx4)0.f;
    if (rin) {
      a0 = *(const floatx4*)&x[(long)arow * H + kb] + *(const floatx4*)&vn[b * H + kb];
      a1 = *(const floatx4*)&x[(long)arow * H + kb + 4] + *(const floatx4*)&vn[b * H + kb + 4];
    }
    af[k0] = pack8(a0, a1);
  }
  __syncthreads();

#pragma unroll
  for (int t = 0; t < 8; t++) {
    floatx4 a = (floatx4)0.f;
#pragma unroll
    for (int k0 = 0; k0 < 4; k0++) {
      int kb = k0 * 32 + quad * 8;
      short8 bf = *(const short8*)&Bs[(t * 16 + mrow) * LDC + kb];
      a = __builtin_amdgcn_mfma_f32_16x16x32_bf16(af[k0], bf, a, 0, 0, 0);
    }
    int c = t * 16 + cn;
#pragma unroll
    for (int i = 0; i < 4; i++) {
      int r = row0 + w * 16 + quad * 4 + i;
      if (r < M) h16[(long)r * H + c] = f2b(a[i]);
    }
  }
}

// ---------------- fused 2-layer FFN: small-LDS variant ----------------
// Hidden transpose is WAVE-PRIVATE: wave w writes its 16 rows and reads the same rows,
// processed in two 128-col halves through a per-wave 16 x LDHW buffer (no barriers).
// LDS: Bs1 (256 x LDK = 18432 sh) overlaid by { HsW 4 x 16 x LDHW = 8704 sh | Bs2 128 x LDK at +8704 }.
// Total 18432 sh = 36864 B -> 4 blocks/CU.
template <int BNRES>
__global__ __launch_bounds__(256) void ffn_fused(const float* __restrict__ A,
                                                 const unsigned short* __restrict__ W1T, const float* __restrict__ b1,
                                                 const unsigned short* __restrict__ W2T, const float* __restrict__ b2,
                                                 const float* __restrict__ scsh,
                                                 float* __restrict__ C, int M) {
  __shared__ unsigned short smem[FFN_SMEM];  // 18432 shorts = 36864 B
  unsigned short* Bs1 = smem;                // phase 1: 256 rows x 64-k slice
  unsigned short* Bs2 = smem + 4 * 16 * LDHW;// phase 2: 128 rows x 64-k slice [8704..17920)

  int tid = threadIdx.x;
  int lane = tid & 63, w = tid >> 6;
  unsigned short* HsW = smem + w * 16 * LDHW;// per-wave hidden half: 16 x LDHW [w*2176 .. +2176)
  int row0 = blockIdx.x * 64;
  int mrow = lane & 15, quad = lane >> 4, cn = lane & 15;
  int arow = row0 + w * 16 + mrow;
  bool rin = arow < M;

  // A fragments direct (fp32 -> bf16 in reg, optional BN). af[k0] covers k = k0*32 .. +31.
  short8 af[4];
#pragma unroll
  for (int k0 = 0; k0 < 4; k0++) {
    int kb = k0 * 32 + quad * 8;
    floatx4 a0 = (floatx4)0.f, a1 = (floatx4)0.f;
    if (rin) {
      a0 = *(const floatx4*)&A[(long)arow * H + kb];
      a1 = *(const floatx4*)&A[(long)arow * H + kb + 4];
      if (BNRES) {
        a0 = a0 * *(const floatx4*)&scsh[kb] + *(const floatx4*)&scsh[H + kb];
        a1 = a1 * *(const floatx4*)&scsh[kb + 4] + *(const floatx4*)&scsh[H + kb + 4];
      }
    }
    af[k0] = pack8(a0, a1);
  }

  // ---- phase 1: hidden = A @ W1 over two 64-k slices; acc held in registers
  floatx4 acc1[16];
#pragma unroll
  for (int t = 0; t < 16; t++) acc1[t] = (floatx4)0.f;

  for (int ks = 0; ks < 2; ks++) {
    if (ks > 0) __syncthreads();
#pragma unroll
    for (int j = 0; j < 8; j++) {
      int chunk = j * 256 + tid;
      int n = chunk >> 3, k8 = (chunk & 7) * 8;
      *(short8*)&Bs1[n * LDK + k8] = *(const short8*)&W1T[(long)n * H + ks * 64 + k8];
    }
    __syncthreads();
#pragma unroll
    for (int t = 0; t < 16; t++) {
      int kb = quad * 8;
      short8 bf0 = *(const short8*)&Bs1[(t * 16 + mrow) * LDK + kb];
      acc1[t] = __builtin_amdgcn_mfma_f32_16x16x32_bf16(af[ks * 2], bf0, acc1[t], 0, 0, 0);
      short8 bf1 = *(const short8*)&Bs1[(t * 16 + mrow) * LDK + 32 + kb];
      acc1[t] = __builtin_amdgcn_mfma_f32_16x16x32_bf16(af[ks * 2 + 1], bf1, acc1[t], 0, 0, 0);
    }
  }
  __syncthreads();  // all waves done reading Bs1 before HsW/Bs2 overwrite it

  // ---- hidden -> A-fragments via per-wave LDS half-buffers (no barriers: intra-wave)
  short8 hf[8];
#pragma unroll
  for (int half = 0; half < 2; half++) {
#pragma unroll
    for (int t = 0; t < 8; t++) {
      int tt = half * 8 + t;
      int cg = tt * 16 + cn;         // global hidden col
      int cl = t * 16 + cn;          // col within half
      float bb = b1[cg];
#pragma unroll
      for (int i = 0; i < 4; i++) {
        int r = quad * 4 + i;        // row within wave's 16
        HsW[r * LDHW + cl] = f2b(gelu_f(acc1[tt][i] + bb));
      }
    }
#pragma unroll
    for (int k0 = 0; k0 < 4; k0++)
      hf[half * 4 + k0] = *(const short8*)&HsW[mrow * LDHW + k0 * 32 + quad * 8];
  }

  // stage W2T slice 0 into Bs2 (disjoint from all HsW regions)
#pragma unroll
  for (int j = 0; j < 4; j++) {
    int chunk = j * 256 + tid;
    int n = chunk >> 3, k8 = (chunk & 7) * 8;
    *(short8*)&Bs2[n * LDK + k8] = *(const short8*)&W2T[(long)n * H2 + k8];
  }
  __syncthreads();

  // ---- phase 2: out = gelu(Hs @ W2 + b2) (+ bn-residual), K = 256 in four 64-k slices
  floatx4 acc2[8];
#pragma unroll
  for (int t = 0; t < 8; t++) acc2[t] = (floatx4)0.f;

  for (int ks = 0; ks < 4; ks++) {
    if (ks > 0) {
      __syncthreads();
#pragma unroll
      for (int j = 0; j < 4; j++) {
        int chunk = j * 256 + tid;
        int n = chunk >> 3, k8 = (chunk & 7) * 8;
        *(short8*)&Bs2[n * LDK + k8] = *(const short8*)&W2T[(long)n * H2 + ks * 64 + k8];
      }
      __syncthreads();
    }
    int kk = ks * 2;
#pragma unroll
    for (int t = 0; t < 8; t++) {
      int kb0 = quad * 8;
      short8 bf0 = *(const short8*)&Bs2[(t * 16 + mrow) * LDK + kb0];
      acc2[t] = __builtin_amdgcn_mfma_f32_16x16x32_bf16(hf[kk], bf0, acc2[t], 0, 0, 0);
      short8 bf1 = *(const short8*)&Bs2[(t * 16 + mrow) * LDK + 32 + kb0];
      acc2[t] = __builtin_amdgcn_mfma_f32_16x16x32_bf16(hf[kk + 1], bf1, acc2[t], 0, 0, 0);
    }
  }

#pragma unroll
  for (int t = 0; t < 8; t++) {
    int c = t * 16 + cn;
    float bb = b2[c];
    float rsc = 0.f, rsh = 0.f;
    if (BNRES) { rsc = scsh[c]; rsh = scsh[H + c]; }
#pragma unroll
    for (int i = 0; i < 4; i++) {
      int r = row0 + w * 16 + quad * 4 + i;
      if (r < M) {
        long off = (long)r * H + c;
        float v = gelu_f(acc2[t][i] + bb);
        if (BNRES) v += C[off] * rsc + rsh;
        C[off] = v;
      }
    }
  }
}

// ---------------- parallel 64-row MLP stages (vn / post) ----------------
template <int BN, int UVN>
__global__ __launch_bounds__(256) void mlp64_l1(const float* __restrict__ vn, const float* __restrict__ pooled,
                                                const float* __restrict__ counts,
                                                const float* __restrict__ W1, const float* __restrict__ b1,
                                                const float* __restrict__ g1, const float* __restrict__ be1,
                                                float* __restrict__ h1) {
  __shared__ float u[64 * H];
  __shared__ float red[8 * 64];
  int t = threadIdx.x;
  for (int idx = t; idx < 64 * H; idx += 256) {
    float v = pooled[idx];
    if (UVN) v = vn[idx] + v / fmaxf(counts[idx >> 7], 1.0f);
    u[idx] = v;
  }
  __syncthreads();
  int tc = t & 63, tg = t >> 6;
  int c = blockIdx.x * 64 + tc;
  float acc[16];
  float bj = b1[c];
#pragma unroll
  for (int g = 0; g < 16; g++) acc[g] = bj;
  for (int k0 = 0; k0 < H; k0 += 4) {
    float w0 = W1[(k0 + 0) * H2 + c];
    float w1 = W1[(k0 + 1) * H2 + c];
    float w2 = W1[(k0 + 2) * H2 + c];
    float w3 = W1[(k0 + 3) * H2 + c];
#pragma unroll
    for (int g = 0; g < 16; g++) {
      float4 v = *(const float4*)&u[(tg * 16 + g) * H + k0];
      acc[g] += v.x * w0 + v.y * w1 + v.z * w2 + v.w * w3;
    }
  }
  float sc = 1.f, sh = 0.f;
  if (BN) {
    float s = 0.f, s2 = 0.f;
#pragma unroll
    for (int g = 0; g < 16; g++) { s += acc[g]; s2 += acc[g] * acc[g]; }
    red[tg * 64 + tc] = s;
    red[256 + tg * 64 + tc] = s2;
    __syncthreads();
    float st = red[tc] + red[64 + tc] + red[128 + tc] + red[192 + tc];
    float st2 = red[256 + tc] + red[320 + tc] + red[384 + tc] + red[448 + tc];
    float m = st * (1.f / 64.f);
    float var = st2 * (1.f / 64.f) - m * m;
    sc = rsqrtf(var + 1e-5f) * g1[c];
    sh = be1[c] - m * sc;
  }
#pragma unroll
  for (int g = 0; g < 16; g++) h1[(tg * 16 + g) * H2 + c] = gelu_f(acc[g] * sc + sh);
}

template <int BN>
__global__ __launch_bounds__(256) void mlp64_l2(const float* __restrict__ h1,
                                                const float* __restrict__ W2, const float* __restrict__ b2,
                                                const float* __restrict__ g2, const float* __restrict__ be2,
                                                float* __restrict__ outp) {
  __shared__ float red[8 * 64];
  int t = threadIdx.x;
  int tc = t & 63, tg = t >> 6;
  int c = blockIdx.x * 64 + tc;
  float acc[16];
  float bj = b2[c];
#pragma unroll
  for (int g = 0; g < 16; g++) acc[g] = bj;
  for (int k0 = 0; k0 < H2; k0 += 4) {
    float w0 = W2[(k0 + 0) * H + c];
    float w1 = W2[(k0 + 1) * H + c];
    float w2 = W2[(k0 + 2) * H + c];
    float w3 = W2[(k0 + 3) * H + c];
#pragma unroll
    for (int g = 0; g < 16; g++) {
      float4 v = *(const float4*)&h1[(tg * 16 + g) * H2 + k0];
      acc[g] += v.x * w0 + v.y * w1 + v.z * w2 + v.w * w3;
    }
  }
  float sc = 1.f, sh = 0.f;
  if (BN) {
    float s = 0.f, s2 = 0.f;
#pragma unroll
    for (int g = 0; g < 16; g++) { s += acc[g]; s2 += acc[g] * acc[g]; }
    red[tg * 64 + tc] = s;
    red[256 + tg * 64 + tc] = s2;
    __syncthreads();
    float st = red[tc] + red[64 + tc] + red[128 + tc] + red[192 + tc];
    float st2 = red[256 + tc] + red[320 + tc] + red[384 + tc] + red[448 + tc];
    float m = st * (1.f / 64.f);
    float var = st2 * (1.f / 64.f) - m * m;
    sc = rsqrtf(var + 1e-5f) * g2[c];
    sh = be2[c] - m * sc;
  }
#pragma unroll
  for (int g = 0; g < 16; g++) outp[(tg * 16 + g) * H + c] = gelu_f(acc[g] * sc + sh);
}

// ---------------- host launch ----------------

extern "C" void kernel_launch(void* const* d_in, const int* in_sizes, int n_in,
                              void* d_out, int out_size, void* d_ws, size_t ws_size,
                              hipStream_t stream) {
  const float* x_in   = (const float*)d_in[0];
  const int*   edge   = (const int*)d_in[1];
  const int*   batch  = (const int*)d_in[2];
  const float* pre_W1 = (const float*)d_in[3];
  const float* pre_b1 = (const float*)d_in[4];
  const float* pre_W2 = (const float*)d_in[5];
  const float* pre_b2 = (const float*)d_in[6];
  const float* conv_W = (const float*)d_in[7];
  const float* conv_b = (const float*)d_in[8];
  const float* bn_g   = (const float*)d_in[9];
  const float* bn_b   = (const float*)d_in[10];
  const float* ffn_W1 = (const float*)d_in[11];
  const float* ffn_b1 = (const float*)d_in[12];
  const float* ffn_W2 = (const float*)d_in[13];
  const float* ffn_b2 = (const float*)d_in[14];
  const float* vn_W1  = (const float*)d_in[15];
  const float* vn_b1  = (const float*)d_in[16];
  const float* vn_g1  = (const float*)d_in[17];
  const float* vn_be1 = (const float*)d_in[18];
  const float* vn_W2  = (const float*)d_in[19];
  const float* vn_b2  = (const float*)d_in[20];
  const float* vn_g2  = (const float*)d_in[21];
  const float* vn_be2 = (const float*)d_in[22];
  const float* vn_emb = (const float*)d_in[23];
  const float* post_W1= (const float*)d_in[24];
  const float* post_b1= (const float*)d_in[25];
  const float* post_W2= (const float*)d_in[26];
  const float* post_b2= (const float*)d_in[27];
  float* out = (float*)d_out;

  const int N    = in_sizes[2];
  const int E    = in_sizes[1] / 2;
  const int G    = out_size / H;
  const int HOPS = in_sizes[7] / (H * H);
  const int NH   = N * H;

  // workspace layout
  float* w = (float*)d_ws;
  float* buf_x  = w;  w += NH;
  float* buf_t  = w;  w += N * H2;
  unsigned short* buf_h16 = (unsigned short*)buf_t;
  float* dinv   = w;  w += N;
  float* counts = w;  w += G;
  float* stats  = w;  w += 2 * H;
  float* scsh   = w;  w += 2 * H;
  float* pooled = w;  w += G * H;
  float* vn     = w;  w += G * H;
  float* mlp_h1 = w;  w += G * H2;
  float* csr_norm = w; w += E;
  int* iw = (int*)w;
  int* cnt      = iw;  iw += N;
  int* row_ptr  = iw;  iw += N + 1;
  int* cursor   = iw;  iw += N;
  int* csr_src  = iw;  iw += E;
  int* blockSum = iw;  iw += 1024;
  int* blockOff = iw;  iw += 1024;
  unsigned short* wt = (unsigned short*)iw;
  unsigned short* preW1T = wt;  wt += H * H2;
  unsigned short* preW2T = wt;  wt += H2 * H;
  unsigned short* convT  = wt;  wt += HOPS * H * H;
  unsigned short* ffn1T  = wt;  wt += HOPS * H * H2;
  unsigned short* ffn2T  = wt;  wt += HOPS * H2 * H;

  const int* src = edge;
  const int* dst = edge + E;

  int gE  = (E + 255) / 256;
  int gM  = (N + 63) / 64;
  int nb  = (N + 1023) / 1024;
  float invN = 1.0f / (float)N;

  // weight transposes
  transpose_w<<<(H * H2 + 255) / 256, 256, 0, stream>>>(pre_W1, preW1T, H, H2, H * H2);
  transpose_w<<<(H2 * H + 255) / 256, 256, 0, stream>>>(pre_W2, preW2T, H2, H, H2 * H);
  transpose_w<<<(HOPS * H * H + 255) / 256, 256, 0, stream>>>(conv_W, convT, H, H, HOPS * H * H);
  transpose_w<<<(HOPS * H * H2 + 255) / 256, 256, 0, stream>>>(ffn_W1, ffn1T, H, H2, HOPS * H * H2);
  transpose_w<<<(HOPS * H2 * H + 255) / 256, 256, 0, stream>>>(ffn_W2, ffn2T, H2, H, HOPS * H2 * H);

  // CSR build + dinv
  hipMemsetAsync(cnt, 0, N * sizeof(int), stream);
  hist_kernel<<<gE, 256, 0, stream>>>(cnt, dst, E);
  scan_a<<<nb, 256, 0, stream>>>(cnt, row_ptr, blockSum, dinv, N);
  scan_b<<<1, 1024, 0, stream>>>(blockSum, blockOff, nb, row_ptr, N, E);
  scan_c<<<nb, 256, 0, stream>>>(row_ptr, blockOff, N);
  hipMemsetAsync(cursor, 0, N * sizeof(int), stream);
  build_csr_kernel<<<gE, 256, 0, stream>>>(src, dst, row_ptr, cursor, dinv, csr_src, csr_norm, E);

  // graph counts, vn init
  hipMemsetAsync(counts, 0, G * sizeof(float), stream);
  count_kernel<<<(N + 256 * 16 - 1) / (256 * 16), 256, 0, stream>>>(counts, batch, N, G);
  vn_init_kernel<<<(G * H + 255) / 256, 256, 0, stream>>>(vn, vn_emb, G * H);

  // pre-FFNN (fused pair)
  ffn_fused<0><<<gM, 256, 0, stream>>>(x_in, preW1T, pre_b1, preW2T, pre_b2, nullptr, buf_x, N);

  for (int i = 0; i < HOPS; i++) {
    // GCN: h16 = bf16( (x + vn[batch]) @ W )
    conv_gemm<<<gM, 256, 0, stream>>>(buf_x, convT + i * H * H, vn, batch, buf_h16, N);
    // x = x + vn[batch] + bias + selfloop + gathered edges; BN stats fused
    hipMemsetAsync(stats, 0, 2 * H * sizeof(float), stream);
    gather_agg<<<(N + 31) / 32, 256, 0, stream>>>(buf_h16, csr_src, csr_norm, row_ptr, dinv, vn, batch,
                                                  conv_b + i * H, buf_x, stats, N);
    bn_finalize_kernel<<<1, 128, 0, stream>>>(stats, bn_g + i * H, bn_b + i * H, scsh, invN);
    // fused FFN: x = gelu(gelu(bn(x)@W1+b1)@W2+b2) + bn(x)
    ffn_fused<1><<<gM, 256, 0, stream>>>(buf_x, ffn1T + i * H * H2, ffn_b1 + i * H2,
                                         ffn2T + i * H2 * H, ffn_b2 + i * H, scsh, buf_x, N);
    // virtual node update
    if (i < HOPS - 1) {
      hipMemsetAsync(pooled, 0, G * H * sizeof(float), stream);
      pool_kernel<<<(N + 127) / 128, 256, 0, stream>>>(pooled, buf_x, batch, N);
      mlp64_l1<1, 1><<<H2 / 64, 256, 0, stream>>>(vn, pooled, counts,
                                                  vn_W1 + i * H * H2, vn_b1 + i * H2, vn_g1 + i * H2, vn_be1 + i * H2,
                                                  mlp_h1);
      mlp64_l2<1><<<H / 64, 256, 0, stream>>>(mlp_h1, vn_W2 + i * H2 * H, vn_b2 + i * H, vn_g2 + i * H, vn_be2 + i * H, vn);
    }
  }

  // final global_add_pool + post-FFNN
  hipMemsetAsync(pooled, 0, G * H * sizeof(float), stream);
  pool_kernel<<<(N + 127) / 128, 256, 0, stream>>>(pooled, buf_x, batch, N);
  mlp64_l1<0, 0><<<H2 / 64, 256, 0, stream>>>(nullptr, pooled, nullptr, post_W1, post_b1, nullptr, nullptr, mlp_h1);
  mlp64_l2<0><<<H / 64, 256, 0, stream>>>(mlp_h1, post_W2, post_b2, nullptr, nullptr, out);
}

// Round 16
// 1813.920 us; speedup vs baseline: 1.0601x; 1.0454x over previous
//
#include <hip/hip_runtime.h>
#include <math.h>

#define H 128
#define H2 256
#define LDK 72    // LDS row stride (bf16) for 64-wide k rows
#define LDC 136   // LDS row stride (bf16) for conv weight rows (128 k)
#define LDHW 136  // LDS row stride (bf16) for per-wave hidden half (128 cols)
#define FFN_SMEM (H2 * LDK)  // 18432 shorts = 36864 B -> 4 blocks/CU

typedef __attribute__((ext_vector_type(8))) short short8;
typedef __attribute__((ext_vector_type(4))) float floatx4;

// fast GELU: x * sigmoid(1.5957691*x*(1+0.044715*x^2)); max |dev| from exact erf-GELU ~1e-3
__device__ __forceinline__ float gelu_f(float x) {
  float t = 1.59576912161f * x * fmaf(0.044715f, x * x, 1.0f);
  return x / (1.0f + __expf(-t));
}

__device__ __forceinline__ unsigned short f2b(float f) {
  union { float f; unsigned u; } c; c.f = f;
  unsigned r = c.u + 0x7fffu + ((c.u >> 16) & 1u);
  return (unsigned short)(r >> 16);
}

__device__ __forceinline__ float b2f(unsigned short u) {
  union { unsigned u; float f; } c; c.u = ((unsigned)u) << 16; return c.f;
}

__device__ __forceinline__ short8 pack8(floatx4 a, floatx4 b) {
  union { short8 v; unsigned short s[8]; } u;
  u.s[0] = f2b(a.x); u.s[1] = f2b(a.y); u.s[2] = f2b(a.z); u.s[3] = f2b(a.w);
  u.s[4] = f2b(b.x); u.s[5] = f2b(b.y); u.s[6] = f2b(b.z); u.s[7] = f2b(b.w);
  return u.v;
}

// ---------------- weight transpose+convert: W[b][K][N] fp32 -> WT[b][N][K] bf16 ----------------
__global__ __launch_bounds__(256) void transpose_w(const float* __restrict__ W, unsigned short* __restrict__ WT,
                                                   int K, int Ncol, int total) {
  int i = blockIdx.x * 256 + threadIdx.x;
  if (i >= total) return;
  int kn = K * Ncol;
  int b = i / kn, r = i - b * kn;
  int k = r / Ncol, n = r - k * Ncol;
  WT[b * kn + n * K + k] = f2b(W[i]);
}

// ---------------- CSR build ----------------

__global__ __launch_bounds__(256) void hist_kernel(int* __restrict__ cnt, const int* __restrict__ dst, int E) {
  int i = blockIdx.x * 256 + threadIdx.x;
  if (i < E) atomicAdd(&cnt[dst[i]], 1);
}

__global__ __launch_bounds__(256) void scan_a(const int* __restrict__ cnt, int* __restrict__ row_ptr,
                                              int* __restrict__ blockSum, float* __restrict__ dinv, int N) {
  __shared__ int ls[256];
  int t = threadIdx.x;
  int idx = blockIdx.x * 1024 + t * 4;
  int4 v = make_int4(0, 0, 0, 0);
  if (idx + 3 < N) v = *(const int4*)&cnt[idx];
  else {
    if (idx + 0 < N) v.x = cnt[idx + 0];
    if (idx + 1 < N) v.y = cnt[idx + 1];
    if (idx + 2 < N) v.z = cnt[idx + 2];
    if (idx + 3 < N) v.w = cnt[idx + 3];
  }
  if (idx + 0 < N) dinv[idx + 0] = rsqrtf((float)v.x + 1.0f);
  if (idx + 1 < N) dinv[idx + 1] = rsqrtf((float)v.y + 1.0f);
  if (idx + 2 < N) dinv[idx + 2] = rsqrtf((float)v.z + 1.0f);
  if (idx + 3 < N) dinv[idx + 3] = rsqrtf((float)v.w + 1.0f);
  int s = v.x + v.y + v.z + v.w;
  ls[t] = s;
  __syncthreads();
  for (int off = 1; off < 256; off <<= 1) {
    int a = (t >= off) ? ls[t - off] : 0;
    __syncthreads();
    ls[t] += a;
    __syncthreads();
  }
  int p = ls[t] - s;
  if (t == 255) blockSum[blockIdx.x] = ls[255];
  if (idx + 0 < N) row_ptr[idx + 0] = p;  p += v.x;
  if (idx + 1 < N) row_ptr[idx + 1] = p;  p += v.y;
  if (idx + 2 < N) row_ptr[idx + 2] = p;  p += v.z;
  if (idx + 3 < N) row_ptr[idx + 3] = p;
}

__global__ __launch_bounds__(1024) void scan_b(const int* __restrict__ blockSum, int* __restrict__ blockOff,
                                               int nb, int* __restrict__ row_ptr, int N, int E) {
  __shared__ int ls[1024];
  int t = threadIdx.x;
  int s = (t < nb) ? blockSum[t] : 0;
  ls[t] = s;
  __syncthreads();
  for (int off = 1; off < 1024; off <<= 1) {
    int a = (t >= off) ? ls[t - off] : 0;
    __syncthreads();
    ls[t] += a;
    __syncthreads();
  }
  if (t < nb) blockOff[t] = ls[t] - s;
  if (t == 0) row_ptr[N] = E;
}

__global__ __launch_bounds__(256) void scan_c(int* __restrict__ row_ptr, const int* __restrict__ blockOff, int N) {
  int t = threadIdx.x;
  int idx = blockIdx.x * 1024 + t * 4;
  int off = blockOff[blockIdx.x];
  if (off == 0) return;
  if (idx + 3 < N) {
    int4 v = *(const int4*)&row_ptr[idx];
    v.x += off; v.y += off; v.z += off; v.w += off;
    *(int4*)&row_ptr[idx] = v;
  } else {
    if (idx + 0 < N) row_ptr[idx + 0] += off;
    if (idx + 1 < N) row_ptr[idx + 1] += off;
    if (idx + 2 < N) row_ptr[idx + 2] += off;
    if (idx + 3 < N) row_ptr[idx + 3] += off;
  }
}

__global__ __launch_bounds__(256) void build_csr_kernel(const int* __restrict__ src, const int* __restrict__ dst,
                                                        const int* __restrict__ row_ptr, int* __restrict__ cursor,
                                                        const float* __restrict__ dinv,
                                                        int* __restrict__ csr_src, float* __restrict__ csr_norm,
                                                        int E) {
  int i = blockIdx.x * 256 + threadIdx.x;
  if (i < E) {
    int s = src[i], d = dst[i];
    int pos = row_ptr[d] + atomicAdd(&cursor[d], 1);
    csr_src[pos] = s;
    csr_norm[pos] = dinv[s] * dinv[d];
  }
}

// ---------------- small setup kernels ----------------

__global__ __launch_bounds__(256) void count_kernel(float* counts, const int* __restrict__ batch, int N, int G) {
  __shared__ float hist[256];
  int t = threadIdx.x;
  if (t < G) hist[t] = 0.f;
  __syncthreads();
  int i0 = (blockIdx.x * 256 + t) * 16;
  int cur = -1; float run = 0.f;
  for (int j = 0; j < 16; j++) {
    int i = i0 + j;
    if (i < N) {
      int b = batch[i];
      if (b == cur) run += 1.f;
      else { if (cur >= 0) atomicAdd(&hist[cur], run); cur = b; run = 1.f; }
    }
  }
  if (cur >= 0) atomicAdd(&hist[cur], run);
  __syncthreads();
  if (t < G && hist[t] != 0.f) atomicAdd(&counts[t], hist[t]);
}

__global__ __launch_bounds__(256) void vn_init_kernel(float* vn, const float* __restrict__ emb, int n) {
  int i = blockIdx.x * 256 + threadIdx.x;
  if (i < n) vn[i] = emb[i & (H - 1)];
}

// ---------------- fused gather aggregation (bf16 h) + BN stats ----------------
// One predicated 8-wide gather group per node (chain depth ~= ceil(deg/8) ~= 1):
// OOB edges clamp index to beg with weight 0 (harmless warm re-read). 8 independent
// loads in flight per group; wave-uniform loop bounds (no divergence).
__global__ __launch_bounds__(256) void gather_agg(const unsigned short* __restrict__ h, const int* __restrict__ csr_src,
                                                  const float* __restrict__ csr_norm, const int* __restrict__ row_ptr,
                                                  const float* __restrict__ dinv, const float* __restrict__ vn,
                                                  const int* __restrict__ batch, const float* __restrict__ bias,
                                                  float* __restrict__ x, float* __restrict__ stats, int N) {
  __shared__ float sred[4 * H];
  __shared__ float qred[4 * H];
  int w = threadIdx.x >> 6, lane = threadIdx.x & 63;
  int c = lane * 2;
  float2 bi = *(const float2*)&bias[c];
  float s0t = 0.f, s1t = 0.f, q0t = 0.f, q1t = 0.f;
  int base = blockIdx.x * 32 + w * 8;
  for (int j = 0; j < 8; j++) {
    int node = base + j;
    if (node >= N) break;
    int b = batch[node];
    float di = dinv[node];
    float2 xo = *(const float2*)&x[(long)node * H + c];
    float2 vv = *(const float2*)&vn[b * H + c];
    unsigned hv = *(const unsigned*)&h[(long)node * H + c];
    int beg = row_ptr[node], end = row_ptr[node + 1];
    float ax = b2f((unsigned short)hv) * di * di;
    float ay = b2f((unsigned short)(hv >> 16)) * di * di;
    for (int e = beg; e < end; e += 8) {
      int si[8]; float wg[8]; unsigned u[8];
#pragma unroll
      for (int i = 0; i < 8; i++) {
        int ee = e + i;
        bool in = ee < end;
        int idx = in ? ee : beg;
        si[i] = csr_src[idx];
        wg[i] = in ? csr_norm[idx] : 0.f;
      }
#pragma unroll
      for (int i = 0; i < 8; i++) u[i] = *(const unsigned*)&h[(long)si[i] * H + c];
#pragma unroll
      for (int i = 0; i < 8; i++) {
        ax += b2f((unsigned short)u[i]) * wg[i];
        ay += b2f((unsigned short)(u[i] >> 16)) * wg[i];
      }
    }
    float rx = ax + xo.x + vv.x + bi.x;
    float ry = ay + xo.y + vv.y + bi.y;
    *(float2*)&x[(long)node * H + c] = make_float2(rx, ry);
    s0t += rx; q0t += rx * rx;
    s1t += ry; q1t += ry * ry;
  }
  sred[w * H + c] = s0t; sred[w * H + c + 1] = s1t;
  qred[w * H + c] = q0t; qred[w * H + c + 1] = q1t;
  __syncthreads();
  int t = threadIdx.x;
  if (t < H) {
    float s = sred[t] + sred[H + t] + sred[2 * H + t] + sred[3 * H + t];
    if (s != 0.f) atomicAdd(&stats[t], s);
  } else {
    int cc = t - H;
    float q = qred[cc] + qred[H + cc] + qred[2 * H + cc] + qred[3 * H + cc];
    if (q != 0.f) atomicAdd(&stats[H + cc], q);
  }
}

// ---------------- BN finalize (stats -> scale/shift) ----------------
__global__ __launch_bounds__(128) void bn_finalize_kernel(const float* __restrict__ stats, const float* __restrict__ g,
                                                          const float* __restrict__ b, float* __restrict__ scsh,
                                                          float invN) {
  int c = threadIdx.x;
  float m = stats[c] * invN;
  float v = stats[H + c] * invN - m * m;
  float sc = rsqrtf(v + 1e-5f) * g[c];
  scsh[c] = sc;
  scsh[H + c] = b[c] - m * sc;
}

// ---------------- pooling (run-length over sorted batch) ----------------
__global__ __launch_bounds__(256) void pool_kernel(float* __restrict__ pooled, const float* __restrict__ x,
                                                   const int* __restrict__ batch, int N) {
  int c = threadIdx.x & 127;
  int slab = threadIdx.x >> 7;
  int r0 = blockIdx.x * 128 + slab;
  float acc = 0.f;
  int cur = -1;
  for (int k = 0; k < 64; k++) {
    int r = r0 + k * 2;
    if (r >= N) break;
    int b = batch[r];
    if (b != cur) {
      if (cur >= 0) atomicAdd(&pooled[cur * H + c], acc);
      cur = b; acc = 0.f;
    }
    acc += x[(long)r * H + c];
  }
  if (cur >= 0) atomicAdd(&pooled[cur * H + c], acc);
}

// ---------------- conv GEMM: B staged once in LDS, A direct->register, 1 barrier ----------------
__global__ __launch_bounds__(256) void conv_gemm(const float* __restrict__ x, const unsigned short* __restrict__ BT,
                                                 const float* __restrict__ vn, const int* __restrict__ batch,
                                                 unsigned short* __restrict__ h16, int M) {
  __shared__ unsigned short Bs[H * LDC];  // 34816 B
  int tid = threadIdx.x;
  int lane = tid & 63, w = tid >> 6;
  int row0 = blockIdx.x * 64;
  int mrow = lane & 15, quad = lane >> 4, cn = lane & 15;
  int arow = row0 + w * 16 + mrow;
  bool rin = arow < M;
  int b = rin ? batch[arow] : 0;

#pragma unroll
  for (int j = 0; j < 8; j++) {
    int chunk = j * 256 + tid;
    int n = chunk >> 4, k8 = (chunk & 15) * 8;
    *(short8*)&Bs[n * LDC + k8] = *(const short8*)&BT[(long)n * H + k8];
  }

  short8 af[4];
#pragma unroll
  for (int k0 = 0; k0 < 4; k0++) {
    int kb = k0 * 32 + quad * 8;
    floatx4 a0 = (floatx4)0.f, a1 = (floatx4)0.f;
    if (rin) {
      a0 = *(const floatx4*)&x[(long)arow * H + kb] + *(const floatx4*)&vn[b * H + kb];
      a1 = *(const floatx4*)&x[(long)arow * H + kb + 4] + *(const floatx4*)&vn[b * H + kb + 4];
    }
    af[k0] = pack8(a0, a1);
  }
  __syncthreads();

#pragma unroll
  for (int t = 0; t < 8; t++) {
    floatx4 a = (floatx4)0.f;
#pragma unroll
    for (int k0 = 0; k0 < 4; k0++) {
      int kb = k0 * 32 + quad * 8;
      short8 bf = *(const short8*)&Bs[(t * 16 + mrow) * LDC + kb];
      a = __builtin_amdgcn_mfma_f32_16x16x32_bf16(af[k0], bf, a, 0, 0, 0);
    }
    int c = t * 16 + cn;
#pragma unroll
    for (int i = 0; i < 4; i++) {
      int r = row0 + w * 16 + quad * 4 + i;
      if (r < M) h16[(long)r * H + c] = f2b(a[i]);
    }
  }
}

// ---------------- fused 2-layer FFN: small-LDS variant (wave-private hidden) ----------------
template <int BNRES>
__global__ __launch_bounds__(256) void ffn_fused(const float* __restrict__ A,
                                                 const unsigned short* __restrict__ W1T, const float* __restrict__ b1,
                                                 const unsigned short* __restrict__ W2T, const float* __restrict__ b2,
                                                 const float* __restrict__ scsh,
                                                 float* __restrict__ C, int M) {
  __shared__ unsigned short smem[FFN_SMEM];  // 18432 shorts = 36864 B
  unsigned short* Bs1 = smem;                // phase 1: 256 rows x 64-k slice
  unsigned short* Bs2 = smem + 4 * 16 * LDHW;// phase 2: 128 rows x 64-k slice [8704..17920)

  int tid = threadIdx.x;
  int lane = tid & 63, w = tid >> 6;
  unsigned short* HsW = smem + w * 16 * LDHW;// per-wave hidden half: 16 x LDHW
  int row0 = blockIdx.x * 64;
  int mrow = lane & 15, quad = lane >> 4, cn = lane & 15;
  int arow = row0 + w * 16 + mrow;
  bool rin = arow < M;

  short8 af[4];
#pragma unroll
  for (int k0 = 0; k0 < 4; k0++) {
    int kb = k0 * 32 + quad * 8;
    floatx4 a0 = (floatx4)0.f, a1 = (floatx4)0.f;
    if (rin) {
      a0 = *(const floatx4*)&A[(long)arow * H + kb];
      a1 = *(const floatx4*)&A[(long)arow * H + kb + 4];
      if (BNRES) {
        a0 = a0 * *(const floatx4*)&scsh[kb] + *(const floatx4*)&scsh[H + kb];
        a1 = a1 * *(const floatx4*)&scsh[kb + 4] + *(const floatx4*)&scsh[H + kb + 4];
      }
    }
    af[k0] = pack8(a0, a1);
  }

  floatx4 acc1[16];
#pragma unroll
  for (int t = 0; t < 16; t++) acc1[t] = (floatx4)0.f;

  for (int ks = 0; ks < 2; ks++) {
    if (ks > 0) __syncthreads();
#pragma unroll
    for (int j = 0; j < 8; j++) {
      int chunk = j * 256 + tid;
      int n = chunk >> 3, k8 = (chunk & 7) * 8;
      *(short8*)&Bs1[n * LDK + k8] = *(const short8*)&W1T[(long)n * H + ks * 64 + k8];
    }
    __syncthreads();
#pragma unroll
    for (int t = 0; t < 16; t++) {
      int kb = quad * 8;
      short8 bf0 = *(const short8*)&Bs1[(t * 16 + mrow) * LDK + kb];
      acc1[t] = __builtin_amdgcn_mfma_f32_16x16x32_bf16(af[ks * 2], bf0, acc1[t], 0, 0, 0);
      short8 bf1 = *(const short8*)&Bs1[(t * 16 + mrow) * LDK + 32 + kb];
      acc1[t] = __builtin_amdgcn_mfma_f32_16x16x32_bf16(af[ks * 2 + 1], bf1, acc1[t], 0, 0, 0);
    }
  }
  __syncthreads();  // all waves done reading Bs1 before HsW/Bs2 overwrite it

  // hidden -> A-fragments via per-wave LDS half-buffers (intra-wave, no barriers)
  short8 hf[8];
#pragma unroll
  for (int half = 0; half < 2; half++) {
#pragma unroll
    for (int t = 0; t < 8; t++) {
      int tt = half * 8 + t;
      int cg = tt * 16 + cn;
      int cl = t * 16 + cn;
      float bb = b1[cg];
#pragma unroll
      for (int i = 0; i < 4; i++) {
        int r = quad * 4 + i;
        HsW[r * LDHW + cl] = f2b(gelu_f(acc1[tt][i] + bb));
      }
    }
#pragma unroll
    for (int k0 = 0; k0 < 4; k0++)
      hf[half * 4 + k0] = *(const short8*)&HsW[mrow * LDHW + k0 * 32 + quad * 8];
  }

#pragma unroll
  for (int j = 0; j < 4; j++) {
    int chunk = j * 256 + tid;
    int n = chunk >> 3, k8 = (chunk & 7) * 8;
    *(short8*)&Bs2[n * LDK + k8] = *(const short8*)&W2T[(long)n * H2 + k8];
  }
  __syncthreads();

  floatx4 acc2[8];
#pragma unroll
  for (int t = 0; t < 8; t++) acc2[t] = (floatx4)0.f;

  for (int ks = 0; ks < 4; ks++) {
    if (ks > 0) {
      __syncthreads();
#pragma unroll
      for (int j = 0; j < 4; j++) {
        int chunk = j * 256 + tid;
        int n = chunk >> 3, k8 = (chunk & 7) * 8;
        *(short8*)&Bs2[n * LDK + k8] = *(const short8*)&W2T[(long)n * H2 + ks * 64 + k8];
      }
      __syncthreads();
    }
    int kk = ks * 2;
#pragma unroll
    for (int t = 0; t < 8; t++) {
      int kb0 = quad * 8;
      short8 bf0 = *(const short8*)&Bs2[(t * 16 + mrow) * LDK + kb0];
      acc2[t] = __builtin_amdgcn_mfma_f32_16x16x32_bf16(hf[kk], bf0, acc2[t], 0, 0, 0);
      short8 bf1 = *(const short8*)&Bs2[(t * 16 + mrow) * LDK + 32 + kb0];
      acc2[t] = __builtin_amdgcn_mfma_f32_16x16x32_bf16(hf[kk + 1], bf1, acc2[t], 0, 0, 0);
    }
  }

#pragma unroll
  for (int t = 0; t < 8; t++) {
    int c = t * 16 + cn;
    float bb = b2[c];
    float rsc = 0.f, rsh = 0.f;
    if (BNRES) { rsc = scsh[c]; rsh = scsh[H + c]; }
#pragma unroll
    for (int i = 0; i < 4; i++) {
      int r = row0 + w * 16 + quad * 4 + i;
      if (r < M) {
        long off = (long)r * H + c;
        float v = gelu_f(acc2[t][i] + bb);
        if (BNRES) v += C[off] * rsc + rsh;
        C[off] = v;
      }
    }
  }
}

// ---------------- parallel 64-row MLP stages (vn / post) ----------------
template <int BN, int UVN>
__global__ __launch_bounds__(256) void mlp64_l1(const float* __restrict__ vn, const float* __restrict__ pooled,
                                                const float* __restrict__ counts,
                                                const float* __restrict__ W1, const float* __restrict__ b1,
                                                const float* __restrict__ g1, const float* __restrict__ be1,
                                                float* __restrict__ h1) {
  __shared__ float u[64 * H];
  __shared__ float red[8 * 64];
  int t = threadIdx.x;
  for (int idx = t; idx < 64 * H; idx += 256) {
    float v = pooled[idx];
    if (UVN) v = vn[idx] + v / fmaxf(counts[idx >> 7], 1.0f);
    u[idx] = v;
  }
  __syncthreads();
  int tc = t & 63, tg = t >> 6;
  int c = blockIdx.x * 64 + tc;
  float acc[16];
  float bj = b1[c];
#pragma unroll
  for (int g = 0; g < 16; g++) acc[g] = bj;
  for (int k0 = 0; k0 < H; k0 += 4) {
    float w0 = W1[(k0 + 0) * H2 + c];
    float w1 = W1[(k0 + 1) * H2 + c];
    float w2 = W1[(k0 + 2) * H2 + c];
    float w3 = W1[(k0 + 3) * H2 + c];
#pragma unroll
    for (int g = 0; g < 16; g++) {
      float4 v = *(const float4*)&u[(tg * 16 + g) * H + k0];
      acc[g] += v.x * w0 + v.y * w1 + v.z * w2 + v.w * w3;
    }
  }
  float sc = 1.f, sh = 0.f;
  if (BN) {
    float s = 0.f, s2 = 0.f;
#pragma unroll
    for (int g = 0; g < 16; g++) { s += acc[g]; s2 += acc[g] * acc[g]; }
    red[tg * 64 + tc] = s;
    red[256 + tg * 64 + tc] = s2;
    __syncthreads();
    float st = red[tc] + red[64 + tc] + red[128 + tc] + red[192 + tc];
    float st2 = red[256 + tc] + red[320 + tc] + red[384 + tc] + red[448 + tc];
    float m = st * (1.f / 64.f);
    float var = st2 * (1.f / 64.f) - m * m;
    sc = rsqrtf(var + 1e-5f) * g1[c];
    sh = be1[c] - m * sc;
  }
#pragma unroll
  for (int g = 0; g < 16; g++) h1[(tg * 16 + g) * H2 + c] = gelu_f(acc[g] * sc + sh);
}

template <int BN>
__global__ __launch_bounds__(256) void mlp64_l2(const float* __restrict__ h1,
                                                const float* __restrict__ W2, const float* __restrict__ b2,
                                                const float* __restrict__ g2, const float* __restrict__ be2,
                                                float* __restrict__ outp) {
  __shared__ float red[8 * 64];
  int t = threadIdx.x;
  int tc = t & 63, tg = t >> 6;
  int c = blockIdx.x * 64 + tc;
  float acc[16];
  float bj = b2[c];
#pragma unroll
  for (int g = 0; g < 16; g++) acc[g] = bj;
  for (int k0 = 0; k0 < H2; k0 += 4) {
    float w0 = W2[(k0 + 0) * H + c];
    float w1 = W2[(k0 + 1) * H + c];
    float w2 = W2[(k0 + 2) * H + c];
    float w3 = W2[(k0 + 3) * H + c];
#pragma unroll
    for (int g = 0; g < 16; g++) {
      float4 v = *(const float4*)&h1[(tg * 16 + g) * H2 + k0];
      acc[g] += v.x * w0 + v.y * w1 + v.z * w2 + v.w * w3;
    }
  }
  float sc = 1.f, sh = 0.f;
  if (BN) {
    float s = 0.f, s2 = 0.f;
#pragma unroll
    for (int g = 0; g < 16; g++) { s += acc[g]; s2 += acc[g] * acc[g]; }
    red[tg * 64 + tc] = s;
    red[256 + tg * 64 + tc] = s2;
    __syncthreads();
    float st = red[tc] + red[64 + tc] + red[128 + tc] + red[192 + tc];
    float st2 = red[256 + tc] + red[320 + tc] + red[384 + tc] + red[448 + tc];
    float m = st * (1.f / 64.f);
    float var = st2 * (1.f / 64.f) - m * m;
    sc = rsqrtf(var + 1e-5f) * g2[c];
    sh = be2[c] - m * sc;
  }
#pragma unroll
  for (int g = 0; g < 16; g++) outp[(tg * 16 + g) * H + c] = gelu_f(acc[g] * sc + sh);
}

// ---------------- host launch ----------------

extern "C" void kernel_launch(void* const* d_in, const int* in_sizes, int n_in,
                              void* d_out, int out_size, void* d_ws, size_t ws_size,
                              hipStream_t stream) {
  const float* x_in   = (const float*)d_in[0];
  const int*   edge   = (const int*)d_in[1];
  const int*   batch  = (const int*)d_in[2];
  const float* pre_W1 = (const float*)d_in[3];
  const float* pre_b1 = (const float*)d_in[4];
  const float* pre_W2 = (const float*)d_in[5];
  const float* pre_b2 = (const float*)d_in[6];
  const float* conv_W = (const float*)d_in[7];
  const float* conv_b = (const float*)d_in[8];
  const float* bn_g   = (const float*)d_in[9];
  const float* bn_b   = (const float*)d_in[10];
  const float* ffn_W1 = (const float*)d_in[11];
  const float* ffn_b1 = (const float*)d_in[12];
  const float* ffn_W2 = (const float*)d_in[13];
  const float* ffn_b2 = (const float*)d_in[14];
  const float* vn_W1  = (const float*)d_in[15];
  const float* vn_b1  = (const float*)d_in[16];
  const float* vn_g1  = (const float*)d_in[17];
  const float* vn_be1 = (const float*)d_in[18];
  const float* vn_W2  = (const float*)d_in[19];
  const float* vn_b2  = (const float*)d_in[20];
  const float* vn_g2  = (const float*)d_in[21];
  const float* vn_be2 = (const float*)d_in[22];
  const float* vn_emb = (const float*)d_in[23];
  const float* post_W1= (const float*)d_in[24];
  const float* post_b1= (const float*)d_in[25];
  const float* post_W2= (const float*)d_in[26];
  const float* post_b2= (const float*)d_in[27];
  float* out = (float*)d_out;

  const int N    = in_sizes[2];
  const int E    = in_sizes[1] / 2;
  const int G    = out_size / H;
  const int HOPS = in_sizes[7] / (H * H);
  const int NH   = N * H;

  // workspace layout
  float* w = (float*)d_ws;
  float* buf_x  = w;  w += NH;
  float* buf_t  = w;  w += N * H2;
  unsigned short* buf_h16 = (unsigned short*)buf_t;
  float* dinv   = w;  w += N;
  float* counts = w;  w += G;
  float* stats  = w;  w += 2 * H;
  float* scsh   = w;  w += 2 * H;
  float* pooled = w;  w += G * H;
  float* vn     = w;  w += G * H;
  float* mlp_h1 = w;  w += G * H2;
  float* csr_norm = w; w += E;
  int* iw = (int*)w;
  int* cnt      = iw;  iw += N;
  int* row_ptr  = iw;  iw += N + 1;
  int* cursor   = iw;  iw += N;
  int* csr_src  = iw;  iw += E;
  int* blockSum = iw;  iw += 1024;
  int* blockOff = iw;  iw += 1024;
  unsigned short* wt = (unsigned short*)iw;
  unsigned short* preW1T = wt;  wt += H * H2;
  unsigned short* preW2T = wt;  wt += H2 * H;
  unsigned short* convT  = wt;  wt += HOPS * H * H;
  unsigned short* ffn1T  = wt;  wt += HOPS * H * H2;
  unsigned short* ffn2T  = wt;  wt += HOPS * H2 * H;

  const int* src = edge;
  const int* dst = edge + E;

  int gE  = (E + 255) / 256;
  int gM  = (N + 63) / 64;
  int nb  = (N + 1023) / 1024;
  float invN = 1.0f / (float)N;

  // weight transposes
  transpose_w<<<(H * H2 + 255) / 256, 256, 0, stream>>>(pre_W1, preW1T, H, H2, H * H2);
  transpose_w<<<(H2 * H + 255) / 256, 256, 0, stream>>>(pre_W2, preW2T, H2, H, H2 * H);
  transpose_w<<<(HOPS * H * H + 255) / 256, 256, 0, stream>>>(conv_W, convT, H, H, HOPS * H * H);
  transpose_w<<<(HOPS * H * H2 + 255) / 256, 256, 0, stream>>>(ffn_W1, ffn1T, H, H2, HOPS * H * H2);
  transpose_w<<<(HOPS * H2 * H + 255) / 256, 256, 0, stream>>>(ffn_W2, ffn2T, H2, H, HOPS * H2 * H);

  // CSR build + dinv
  hipMemsetAsync(cnt, 0, N * sizeof(int), stream);
  hist_kernel<<<gE, 256, 0, stream>>>(cnt, dst, E);
  scan_a<<<nb, 256, 0, stream>>>(cnt, row_ptr, blockSum, dinv, N);
  scan_b<<<1, 1024, 0, stream>>>(blockSum, blockOff, nb, row_ptr, N, E);
  scan_c<<<nb, 256, 0, stream>>>(row_ptr, blockOff, N);
  hipMemsetAsync(cursor, 0, N * sizeof(int), stream);
  build_csr_kernel<<<gE, 256, 0, stream>>>(src, dst, row_ptr, cursor, dinv, csr_src, csr_norm, E);

  // graph counts, vn init
  hipMemsetAsync(counts, 0, G * sizeof(float), stream);
  count_kernel<<<(N + 256 * 16 - 1) / (256 * 16), 256, 0, stream>>>(counts, batch, N, G);
  vn_init_kernel<<<(G * H + 255) / 256, 256, 0, stream>>>(vn, vn_emb, G * H);

  // pre-FFNN (fused pair)
  ffn_fused<0><<<gM, 256, 0, stream>>>(x_in, preW1T, pre_b1, preW2T, pre_b2, nullptr, buf_x, N);

  for (int i = 0; i < HOPS; i++) {
    // GCN: h16 = bf16( (x + vn[batch]) @ W )
    conv_gemm<<<gM, 256, 0, stream>>>(buf_x, convT + i * H * H, vn, batch, buf_h16, N);
    // x = x + vn[batch] + bias + selfloop + gathered edges; BN stats fused
    hipMemsetAsync(stats, 0, 2 * H * sizeof(float), stream);
    gather_agg<<<(N + 31) / 32, 256, 0, stream>>>(buf_h16, csr_src, csr_norm, row_ptr, dinv, vn, batch,
                                                  conv_b + i * H, buf_x, stats, N);
    bn_finalize_kernel<<<1, 128, 0, stream>>>(stats, bn_g + i * H, bn_b + i * H, scsh, invN);
    // fused FFN: x = gelu(gelu(bn(x)@W1+b1)@W2+b2) + bn(x)
    ffn_fused<1><<<gM, 256, 0, stream>>>(buf_x, ffn1T + i * H * H2, ffn_b1 + i * H2,
                                         ffn2T + i * H2 * H, ffn_b2 + i * H, scsh, buf_x, N);
    // virtual node update
    if (i < HOPS - 1) {
      hipMemsetAsync(pooled, 0, G * H * sizeof(float), stream);
      pool_kernel<<<(N + 127) / 128, 256, 0, stream>>>(pooled, buf_x, batch, N);
      mlp64_l1<1, 1><<<H2 / 64, 256, 0, stream>>>(vn, pooled, counts,
                                                  vn_W1 + i * H * H2, vn_b1 + i * H2, vn_g1 + i * H2, vn_be1 + i * H2,
                                                  mlp_h1);
      mlp64_l2<1><<<H / 64, 256, 0, stream>>>(mlp_h1, vn_W2 + i * H2 * H, vn_b2 + i * H, vn_g2 + i * H, vn_be2 + i * H, vn);
    }
  }

  // final global_add_pool + post-FFNN
  hipMemsetAsync(pooled, 0, G * H * sizeof(float), stream);
  pool_kernel<<<(N + 127) / 128, 256, 0, stream>>>(pooled, buf_x, batch, N);
  mlp64_l1<0, 0><<<H2 / 64, 256, 0, stream>>>(nullptr, pooled, nullptr, post_W1, post_b1, nullptr, nullptr, mlp_h1);
  mlp64_l2<0><<<H / 64, 256, 0, stream>>>(mlp_h1, post_W2, post_b2, nullptr, nullptr, out);
}